// Round 2
// baseline (776.545 us; speedup 1.0000x reference)
//
#include <hip/hip_runtime.h>
#include <hip/hip_bf16.h>

typedef unsigned short u16;
typedef unsigned int   u32;

// N=50000, F=64, H=128, HEADS=4, C=32, L=3, E=800000, G=512, DG=32, NC=1
#define HD 128
#define FD 64
#define EPS 1e-5f

__device__ __forceinline__ float b2f(u16 v) { return __uint_as_float(((u32)v) << 16); }
__device__ __forceinline__ u16 f2b(float f) {
    u32 u = __float_as_uint(f);
    return (u16)((u + 0x7FFF + ((u >> 16) & 1)) >> 16);  // RNE
}
__device__ __forceinline__ float lo16(u32 u) { return __uint_as_float(u << 16); }
__device__ __forceinline__ float hi16(u32 u) { return __uint_as_float(u & 0xFFFF0000u); }

// ---------------- dtype probe: 1 = bf16-packed, 0 = float32 ----------------
// For bf16 pairs, bits[14:7] of each u16 are the bf16 exponent (~127 for N(0,1)).
// For f32 words, bits[14:7] are low mantissa bits (uniform).
__global__ __launch_bounds__(256) void k_probe(const u32* __restrict__ x, int* __restrict__ flag, int nwords) {
    __shared__ int s[256];
    int tid = threadIdx.x;
    int cnt = 0;
    for (int i = tid; i < nwords; i += 256) {
        u32 e = (x[i] >> 7) & 0xFF;
        cnt += (e >= 100 && e <= 140) ? 1 : 0;
    }
    s[tid] = cnt;
    __syncthreads();
    for (int off = 128; off > 0; off >>= 1) {
        if (tid < off) s[tid] += s[tid + off];
        __syncthreads();
    }
    if (tid == 0) *flag = (s[0] * 10 > nwords * 6) ? 1 : 0;
}

// ---------------- normalize all float inputs to bf16 in workspace ----------------
#define NCVT 26
struct CvtArgs {
    const void* src[NCVT];
    u32 dstoff[NCVT];   // element (u16) offsets into dstbase; always even
    int elems[NCVT];
};

__global__ __launch_bounds__(256) void k_convert(CvtArgs a, u16* __restrict__ dstbase,
                                                 const int* __restrict__ flag) {
    int ai = blockIdx.y;
    int elems = a.elems[ai];
    int words = (elems + 1) >> 1;
    u32* d = (u32*)(dstbase + a.dstoff[ai]);
    bool isbf = (*flag != 0);
    if (isbf) {
        const u16* s16 = (const u16*)a.src[ai];
        for (int i = blockIdx.x * 256 + threadIdx.x; i < words; i += gridDim.x * 256) {
            if (2 * i + 1 < elems) d[i] = ((const u32*)s16)[i];
            else d[i] = (u32)s16[2 * i];  // odd tail: 2-byte read only
        }
    } else {
        const float* s = (const float*)a.src[ai];
        for (int i = blockIdx.x * 256 + threadIdx.x; i < words; i += gridDim.x * 256) {
            u16 b0 = f2b(s[2 * i]);
            u16 b1 = (2 * i + 1 < elems) ? f2b(s[2 * i + 1]) : (u16)0;
            d[i] = (u32)b0 | ((u32)b1 << 16);
        }
    }
}

// ---------------- CSR build ----------------
__global__ __launch_bounds__(256) void k_hist(const int* __restrict__ dst, int* __restrict__ cnt, int E) {
    int e = blockIdx.x * 256 + threadIdx.x;
    if (e < E) atomicAdd(&cnt[dst[e]], 1);
}

__global__ __launch_bounds__(256) void k_scanA(const int* __restrict__ cnt, int* __restrict__ rowptr,
                                               int* __restrict__ bsum, int N) {
    __shared__ int s[256];
    int tid = threadIdx.x;
    int i = blockIdx.x * 256 + tid;
    s[tid] = (i < N) ? cnt[i] : 0;
    __syncthreads();
    for (int off = 1; off < 256; off <<= 1) {
        int t = (tid >= off) ? s[tid - off] : 0;
        __syncthreads();
        s[tid] += t;
        __syncthreads();
    }
    if (i < N) rowptr[i + 1] = s[tid];
    if (tid == 255) bsum[blockIdx.x] = s[255];
}

__global__ __launch_bounds__(256) void k_scanB(int* __restrict__ bsum, int SB) {
    __shared__ int s[256];
    int tid = threadIdx.x;
    s[tid] = (tid < SB) ? bsum[tid] : 0;
    __syncthreads();
    for (int off = 1; off < 256; off <<= 1) {
        int t = (tid >= off) ? s[tid - off] : 0;
        __syncthreads();
        s[tid] += t;
        __syncthreads();
    }
    if (tid < SB) bsum[tid] = s[tid];
}

__global__ __launch_bounds__(256) void k_scanC(int* __restrict__ rowptr, const int* __restrict__ bsum, int N) {
    int i = blockIdx.x * 256 + threadIdx.x;
    if (i == 0) rowptr[0] = 0;
    if (i < N) {
        int b = i >> 8;
        if (b > 0) rowptr[i + 1] += bsum[b - 1];
    }
}

__global__ __launch_bounds__(256) void k_scatter(const int* __restrict__ src, const int* __restrict__ dst,
                                                 const int* __restrict__ rowptr, int* __restrict__ fill,
                                                 int* __restrict__ colidx, int E) {
    int e = blockIdx.x * 256 + threadIdx.x;
    if (e < E) {
        int d = dst[e];
        int slot = atomicAdd(&fill[d], 1);
        colidx[rowptr[d] + slot] = src[e];
    }
}

// ---------------- node encoder: h = relu(bn(x @ W + b)) ----------------
__global__ __launch_bounds__(256) void k_node_enc(
    const u16* __restrict__ x, const u16* __restrict__ W, const u16* __restrict__ bias,
    const u16* __restrict__ g, const u16* __restrict__ bb, const u16* __restrict__ m,
    const u16* __restrict__ v, u16* __restrict__ h, int N) {
    __shared__ float Wf[FD][HD];   // BN-folded weights, 32KB
    __shared__ float bf[HD];
    __shared__ float xs[2][FD];
    int tid = threadIdx.x;
    if (tid < HD) {
        float sc = b2f(g[tid]) * rsqrtf(b2f(v[tid]) + EPS);
        bf[tid] = (b2f(bias[tid]) - b2f(m[tid])) * sc + b2f(bb[tid]);
    }
    for (int i = tid; i < FD * HD; i += 256) {
        int k = i / HD, j = i % HD;
        float sc = b2f(g[j]) * rsqrtf(b2f(v[j]) + EPS);
        Wf[k][j] = b2f(W[i]) * sc;
    }
    __syncthreads();
    int j = tid & 127;
    int gq = tid >> 7;  // 0..1
    int pairs = (N + 1) >> 1;
    for (int pp = blockIdx.x; pp < pairs; pp += gridDim.x) {
        int n0 = 2 * pp;
        if (tid < FD) xs[0][tid] = b2f(x[(size_t)n0 * FD + tid]);
        else if (tid < 2 * FD) { if (n0 + 1 < N) xs[1][tid - FD] = b2f(x[(size_t)(n0 + 1) * FD + tid - FD]); }
        __syncthreads();
        int n = n0 + gq;
        if (n < N) {
            float acc = bf[j];
            #pragma unroll 8
            for (int k = 0; k < FD; k++) acc += xs[gq][k] * Wf[k][j];
            h[(size_t)n * HD + j] = f2b(fmaxf(acc, 0.f));
        }
        __syncthreads();
    }
}

// ---------------- GAT linear: hh = h @ lin; a_src/a_dst fused ----------------
__global__ __launch_bounds__(256) void k_gat_gemm(
    const u16* __restrict__ h, const u32* __restrict__ Wl32,
    const u16* __restrict__ asrcp, const u16* __restrict__ adstp,
    u32* __restrict__ hh32, float* __restrict__ a_src, float* __restrict__ a_dst, int N) {
    __shared__ u32 Wp[HD][64];        // bf16-pairs, 32KB
    __shared__ float ht[32][HD + 1];  // 16.5KB
    int tid = threadIdx.x;
    for (int i = tid; i < HD * 64; i += 256) Wp[i >> 6][i & 63] = Wl32[i];
    int nb = blockIdx.x * 32;
    for (int i = tid; i < 32 * HD; i += 256) {
        int n = i >> 7, k = i & 127;
        int gn = nb + n;
        ht[n][k] = (gn < N) ? b2f(h[(size_t)gn * HD + k]) : 0.f;
    }
    __syncthreads();
    int cg = tid & 31;   // cols cg*4 .. cg*4+3
    int ng = tid >> 5;   // local nodes ng*4 .. ng*4+3
    float acc[4][4];
    #pragma unroll
    for (int r = 0; r < 4; r++)
        #pragma unroll
        for (int q = 0; q < 4; q++) acc[r][q] = 0.f;
    for (int k = 0; k < HD; k++) {
        u32 w01 = Wp[k][cg * 2], w23 = Wp[k][cg * 2 + 1];
        float w0 = lo16(w01), w1 = hi16(w01), w2 = lo16(w23), w3 = hi16(w23);
        #pragma unroll
        for (int r = 0; r < 4; r++) {
            float hv = ht[ng * 4 + r][k];
            acc[r][0] += hv * w0; acc[r][1] += hv * w1;
            acc[r][2] += hv * w2; acc[r][3] += hv * w3;
        }
    }
    int head = cg >> 3;
    float as0 = b2f(asrcp[cg * 4 + 0]), as1 = b2f(asrcp[cg * 4 + 1]);
    float as2 = b2f(asrcp[cg * 4 + 2]), as3 = b2f(asrcp[cg * 4 + 3]);
    float ad0 = b2f(adstp[cg * 4 + 0]), ad1 = b2f(adstp[cg * 4 + 1]);
    float ad2 = b2f(adstp[cg * 4 + 2]), ad3 = b2f(adstp[cg * 4 + 3]);
    #pragma unroll
    for (int r = 0; r < 4; r++) {
        int n = nb + ng * 4 + r;
        float ps = acc[r][0] * as0 + acc[r][1] * as1 + acc[r][2] * as2 + acc[r][3] * as3;
        float pd = acc[r][0] * ad0 + acc[r][1] * ad1 + acc[r][2] * ad2 + acc[r][3] * ad3;
        #pragma unroll
        for (int msk = 1; msk < 8; msk <<= 1) {
            ps += __shfl_xor(ps, msk);
            pd += __shfl_xor(pd, msk);
        }
        if (n < N) {
            u32 p01 = (u32)f2b(acc[r][0]) | ((u32)f2b(acc[r][1]) << 16);
            u32 p23 = (u32)f2b(acc[r][2]) | ((u32)f2b(acc[r][3]) << 16);
            hh32[(size_t)n * 64 + cg * 2] = p01;
            hh32[(size_t)n * 64 + cg * 2 + 1] = p23;
            if ((cg & 7) == 0) {
                a_src[n * 4 + head] = ps;
                a_dst[n * 4 + head] = pd;
            }
        }
    }
}

// ---------------- per-node attention aggregation (one wave per node) ----------------
__global__ __launch_bounds__(256) void k_agg(
    u16* __restrict__ h, const u32* __restrict__ hh32,
    const float* __restrict__ a_src, const float* __restrict__ a_dst,
    const int* __restrict__ rowptr, const int* __restrict__ colidx,
    const u16* __restrict__ bias, const u16* __restrict__ bng, const u16* __restrict__ bnb,
    const u16* __restrict__ bnm, const u16* __restrict__ bnv, int N) {
    int node = (blockIdx.x * 256 + threadIdx.x) >> 6;
    int lane = threadIdx.x & 63;
    if (node >= N) return;
    int head = lane >> 4;           // cols 2*lane, 2*lane+1 -> head = lane/16
    float adst = a_dst[node * 4 + head];
    // self loop (PyG GATConv adds it)
    float e = a_src[node * 4 + head] + adst;
    e = (e > 0.f) ? e : 0.2f * e;
    float ee = __expf(e);
    float den = ee;
    u32 hv = hh32[(size_t)node * 64 + lane];
    float acc0 = ee * lo16(hv), acc1 = ee * hi16(hv);
    int beg = rowptr[node], end = rowptr[node + 1];
    for (int k = beg; k < end; k++) {
        int s = colidx[k];
        float e2 = a_src[s * 4 + head] + adst;
        e2 = (e2 > 0.f) ? e2 : 0.2f * e2;
        float ee2 = __expf(e2);
        den += ee2;
        u32 hv2 = hh32[(size_t)s * 64 + lane];
        acc0 += ee2 * lo16(hv2);
        acc1 += ee2 * hi16(hv2);
    }
    float inv = 1.0f / (den + 1e-16f);
    int c0 = lane * 2, c1 = c0 + 1;
    float o0 = acc0 * inv, o1 = acc1 * inv;
    float sc0 = b2f(bng[c0]) * rsqrtf(b2f(bnv[c0]) + EPS);
    float sc1 = b2f(bng[c1]) * rsqrtf(b2f(bnv[c1]) + EPS);
    o0 = (o0 + b2f(bias[c0]) - b2f(bnm[c0])) * sc0 + b2f(bnb[c0]);
    o1 = (o1 + b2f(bias[c1]) - b2f(bnm[c1])) * sc1 + b2f(bnb[c1]);
    o0 = fmaxf(o0, 0.f); o1 = fmaxf(o1, 0.f);
    u32 idv = ((const u32*)h)[(size_t)node * 64 + lane];  // residual identity
    o0 += lo16(idv); o1 += hi16(idv);
    ((u32*)h)[(size_t)node * 64 + lane] = ((u32)f2b(o1) << 16) | f2b(o0);
}

// ---------------- per-graph mean/max pooling ----------------
__global__ __launch_bounds__(128) void k_pool(
    const u16* __restrict__ h, const int* __restrict__ batch,
    float* __restrict__ z, int N, int G) {
    int g = blockIdx.x;
    int tid = threadIdx.x;
    int lo = 0, hi = N;
    while (lo < hi) { int mid = (lo + hi) >> 1; if (batch[mid] < g) lo = mid + 1; else hi = mid; }
    int beg = lo;
    hi = N;
    while (lo < hi) { int mid = (lo + hi) >> 1; if (batch[mid] <= g) lo = mid + 1; else hi = mid; }
    int end = lo;
    float s = 0.f, mx = -3.4e38f;
    for (int r = beg; r < end; r++) {
        float v = b2f(h[(size_t)r * HD + tid]);
        s += v;
        mx = fmaxf(mx, v);
    }
    int cnt = end - beg;
    float mean = s / (float)(cnt > 0 ? cnt : 1);
    if (cnt == 0) mx = 0.f;  // isfinite guard in reference
    z[(size_t)g * 384 + tid] = mean;
    z[(size_t)g * 384 + 128 + tid] = mx;
}

// ---------------- global-feature encoder ----------------
__global__ __launch_bounds__(128) void k_glob(
    const u16* __restrict__ gf, const u16* __restrict__ W, const u16* __restrict__ b,
    const u16* __restrict__ g_, const u16* __restrict__ bb, const u16* __restrict__ m_,
    const u16* __restrict__ v_, float* __restrict__ z, int G) {
    int g = blockIdx.x, j = threadIdx.x;
    float acc = b2f(b[j]);
    #pragma unroll 8
    for (int k = 0; k < 32; k++) acc += b2f(gf[g * 32 + k]) * b2f(W[k * HD + j]);
    float sc = b2f(g_[j]) * rsqrtf(b2f(v_[j]) + EPS);
    acc = (acc - b2f(m_[j])) * sc + b2f(bb[j]);
    z[(size_t)g * 384 + 256 + j] = fmaxf(acc, 0.f);
}

// ---------------- final head: relu(z @ W1 + b1) @ W2 + b2 ----------------
__global__ __launch_bounds__(128) void k_final(
    const float* __restrict__ z, const u16* __restrict__ W1, const u16* __restrict__ b1,
    const u16* __restrict__ W2, const u16* __restrict__ b2, void* __restrict__ out,
    const int* __restrict__ flag, int G) {
    __shared__ float zs[384];
    __shared__ float red[128];
    int g = blockIdx.x, tid = threadIdx.x;
    for (int i = tid; i < 384; i += 128) zs[i] = z[(size_t)g * 384 + i];
    __syncthreads();
    float acc = b2f(b1[tid]);
    #pragma unroll 4
    for (int k = 0; k < 384; k++) acc += zs[k] * b2f(W1[k * HD + tid]);
    acc = fmaxf(acc, 0.f);
    red[tid] = acc * b2f(W2[tid]);
    __syncthreads();
    for (int sft = 64; sft > 0; sft >>= 1) {
        if (tid < sft) red[tid] += red[tid + sft];
        __syncthreads();
    }
    if (tid == 0) {
        float r = red[0] + b2f(b2[0]);
        if (*flag) ((u16*)out)[g] = f2b(r);
        else ((float*)out)[g] = r;
    }
}

extern "C" void kernel_launch(void* const* d_in, const int* in_sizes, int n_in,
                              void* d_out, int out_size, void* d_ws, size_t ws_size,
                              hipStream_t stream) {
    (void)n_in; (void)out_size; (void)ws_size;
    const int* ei    = (const int*)d_in[3];
    const int* batch = (const int*)d_in[4];

    const int N = in_sizes[0] / FD;
    const int E = in_sizes[3] / 2;
    const int G = in_sizes[2] / 32;
    const int* srcp = ei;
    const int* dstp = ei + E;

    char* p = (char*)d_ws;
    auto alloc = [&](size_t bytes) -> char* {
        char* r = p;
        p += (bytes + 255) & ~(size_t)255;
        return r;
    };
    u16*   h      = (u16*)alloc((size_t)N * HD * 2);
    u16*   hh     = (u16*)alloc((size_t)N * HD * 2);
    float* a_src  = (float*)alloc((size_t)N * 4 * 4);
    float* a_dst  = (float*)alloc((size_t)N * 4 * 4);
    int*   rowptr = (int*)alloc((size_t)(N + 1) * 4);
    int*   cnt    = (int*)alloc((size_t)N * 4);
    int*   fill   = (int*)alloc((size_t)N * 4);
    int*   bsum   = (int*)alloc(256 * 4);
    int*   colidx = (int*)alloc((size_t)E * 4);
    float* z      = (float*)alloc((size_t)G * 384 * 4);
    int*   dflag  = (int*)alloc(256);

    // bf16-normalized copies of the 26 used float inputs
    static const int cvt_idx[NCVT] = {0, 2, 5, 6, 7, 8, 9, 10, 13, 14, 15, 16, 17, 18,
                                      19, 20, 21, 22, 23, 24, 25, 26, 27, 28, 29, 30};
    CvtArgs ca;
    u32 coff = 0;
    const u16* cvt[32];
    for (int i = 0; i < NCVT; i++) {
        int gi = cvt_idx[i];
        ca.src[i] = d_in[gi];
        ca.elems[i] = in_sizes[gi];
        ca.dstoff[i] = coff;
        coff += (u32)((in_sizes[gi] + 1) & ~1);  // keep 4B alignment
    }
    u16* cvtbase = (u16*)alloc((size_t)coff * 2);
    for (int i = 0; i < NCVT; i++) cvt[cvt_idx[i]] = cvtbase + ca.dstoff[i];

    const u16* x        = cvt[0];
    const u16* gfeat    = cvt[2];
    const u16* node_w   = cvt[5];
    const u16* node_b   = cvt[6];
    const u16* nbg      = cvt[7];
    const u16* nbb      = cvt[8];
    const u16* nbm      = cvt[9];
    const u16* nbv      = cvt[10];
    const u16* glob_w   = cvt[13];
    const u16* glob_b   = cvt[14];
    const u16* gbg      = cvt[15];
    const u16* gbb      = cvt[16];
    const u16* gbm      = cvt[17];
    const u16* gbv      = cvt[18];
    const u16* gat_lin  = cvt[19];
    const u16* gat_asrc = cvt[20];
    const u16* gat_adst = cvt[21];
    const u16* gat_bias = cvt[22];
    const u16* bn_g     = cvt[23];
    const u16* bn_b     = cvt[24];
    const u16* bn_m     = cvt[25];
    const u16* bn_v     = cvt[26];
    const u16* lin1_w   = cvt[27];
    const u16* lin1_b   = cvt[28];
    const u16* lin2_w   = cvt[29];
    const u16* lin2_b   = cvt[30];

    hipMemsetAsync(cnt, 0, (size_t)N * 4, stream);
    hipMemsetAsync(fill, 0, (size_t)N * 4, stream);

    int probe_words = 4096;
    if (in_sizes[0] / 2 < probe_words) probe_words = in_sizes[0] / 2;
    k_probe<<<1, 256, 0, stream>>>((const u32*)d_in[0], dflag, probe_words);
    k_convert<<<dim3(512, NCVT), 256, 0, stream>>>(ca, cvtbase, dflag);

    int eb = (E + 255) / 256;
    int SB = (N + 255) / 256;  // 196 <= 256, single-block second-level scan OK
    k_hist<<<eb, 256, 0, stream>>>(dstp, cnt, E);
    k_scanA<<<SB, 256, 0, stream>>>(cnt, rowptr, bsum, N);
    k_scanB<<<1, 256, 0, stream>>>(bsum, SB);
    k_scanC<<<SB, 256, 0, stream>>>(rowptr, bsum, N);
    k_scatter<<<eb, 256, 0, stream>>>(srcp, dstp, rowptr, fill, colidx, E);

    k_node_enc<<<512, 256, 0, stream>>>(x, node_w, node_b, nbg, nbb, nbm, nbv, h, N);

    for (int i = 0; i < 3; i++) {
        k_gat_gemm<<<(N + 31) / 32, 256, 0, stream>>>(
            h, (const u32*)(gat_lin + (size_t)i * HD * HD),
            gat_asrc + i * HD, gat_adst + i * HD,
            (u32*)hh, a_src, a_dst, N);
        k_agg<<<(N + 3) / 4, 256, 0, stream>>>(
            h, (const u32*)hh, a_src, a_dst, rowptr, colidx,
            gat_bias + i * HD, bn_g + i * HD, bn_b + i * HD, bn_m + i * HD, bn_v + i * HD, N);
    }

    k_pool<<<G, 128, 0, stream>>>(h, batch, z, N, G);
    k_glob<<<G, 128, 0, stream>>>(gfeat, glob_w, glob_b, gbg, gbb, gbm, gbv, z, G);
    k_final<<<G, 128, 0, stream>>>(z, lin1_w, lin1_b, lin2_w, lin2_b, d_out, dflag, G);
}

// Round 4
// 464.938 us; speedup vs baseline: 1.6702x; 1.6702x over previous
//
#include <hip/hip_runtime.h>
#include <hip/hip_bf16.h>

typedef unsigned short u16;
typedef unsigned int   u32;

// N=50000, F=64, H=128, HEADS=4, C=32, L=3, E=800000, G=512, DG=32, NC=1
// All float inputs/outputs are FLOAT32 (established round 2/3 A-B evidence).
// Internal node features h/hh are bf16 for MFMA.
#define HD 128
#define FD 64
#define EPS 1e-5f

using bf16x8 = __attribute__((ext_vector_type(8))) short;
using f32x4  = __attribute__((ext_vector_type(4))) float;

__device__ __forceinline__ float b2f(u16 v) { return __uint_as_float(((u32)v) << 16); }
__device__ __forceinline__ u16 f2b(float f) {
    u32 u = __float_as_uint(f);
    return (u16)((u + 0x7FFF + ((u >> 16) & 1)) >> 16);  // RNE
}
__device__ __forceinline__ float lo16(u32 u) { return __uint_as_float(u << 16); }
__device__ __forceinline__ float hi16(u32 u) { return __uint_as_float(u & 0xFFFF0000u); }

__device__ __forceinline__ bf16x8 pack8(const float* p) {
    bf16x8 r;
    #pragma unroll
    for (int j = 0; j < 8; j++) r[j] = (short)f2b(p[j]);
    return r;
}

// ---------------- CSR build ----------------
__global__ __launch_bounds__(256) void k_hist(const int* __restrict__ dst, int* __restrict__ cnt, int E) {
    int e = blockIdx.x * 256 + threadIdx.x;
    if (e < E) atomicAdd(&cnt[dst[e]], 1);
}

__global__ __launch_bounds__(256) void k_scanA(const int* __restrict__ cnt, int* __restrict__ rowptr,
                                               int* __restrict__ bsum, int N) {
    __shared__ int s[256];
    int tid = threadIdx.x;
    int i = blockIdx.x * 256 + tid;
    s[tid] = (i < N) ? cnt[i] : 0;
    __syncthreads();
    for (int off = 1; off < 256; off <<= 1) {
        int t = (tid >= off) ? s[tid - off] : 0;
        __syncthreads();
        s[tid] += t;
        __syncthreads();
    }
    if (i < N) rowptr[i + 1] = s[tid];
    if (tid == 255) bsum[blockIdx.x] = s[255];
}

__global__ __launch_bounds__(256) void k_scanB(int* __restrict__ bsum, int SB) {
    __shared__ int s[256];
    int tid = threadIdx.x;
    s[tid] = (tid < SB) ? bsum[tid] : 0;
    __syncthreads();
    for (int off = 1; off < 256; off <<= 1) {
        int t = (tid >= off) ? s[tid - off] : 0;
        __syncthreads();
        s[tid] += t;
        __syncthreads();
    }
    if (tid < SB) bsum[tid] = s[tid];
}

__global__ __launch_bounds__(256) void k_scanC(int* __restrict__ rowptr, const int* __restrict__ bsum, int N) {
    int i = blockIdx.x * 256 + threadIdx.x;
    if (i == 0) rowptr[0] = 0;
    if (i < N) {
        int b = i >> 8;
        if (b > 0) rowptr[i + 1] += bsum[b - 1];
    }
}

__global__ __launch_bounds__(256) void k_scatter(const int* __restrict__ src, const int* __restrict__ dst,
                                                 const int* __restrict__ rowptr, int* __restrict__ fill,
                                                 int* __restrict__ colidx, int E) {
    int e = blockIdx.x * 256 + threadIdx.x;
    if (e < E) {
        int d = dst[e];
        int slot = atomicAdd(&fill[d], 1);
        colidx[rowptr[d] + slot] = src[e];
    }
}

// ---------------- weight fragment prep (f32 -> bf16 MFMA B-operand) ----------------
// frag f = ((ct*KT + kt)*64 + lane)*8 + j  holds  W[kt*32 + (lane>>4)*8 + j][ct*16 + (lane&15)]
__global__ __launch_bounds__(256) void k_wprep(const float* __restrict__ node_w, const float* __restrict__ gat_lin,
                                               u16* __restrict__ wf_node, u16* __restrict__ wf_gat) {
    int y = blockIdx.y;
    const float* src; u16* dst; int K;
    if (y == 0) { src = node_w; dst = wf_node; K = FD; }
    else { src = gat_lin + (size_t)(y - 1) * HD * HD; dst = wf_gat + (size_t)(y - 1) * HD * HD; K = HD; }
    int KT = K >> 5;
    int total = K * HD;
    for (int f = blockIdx.x * 256 + threadIdx.x; f < total; f += gridDim.x * 256) {
        int j = f & 7;
        int lane = (f >> 3) & 63;
        int t = f >> 9;           // ct*KT + kt
        int kt = t % KT;
        int ct = t / KT;
        int k = kt * 32 + (lane >> 4) * 8 + j;
        int col = ct * 16 + (lane & 15);
        dst[f] = f2b(src[k * HD + col]);
    }
}

// ---------------- node encoder via MFMA: h = relu(bn(x @ W + b)) ----------------
__global__ __launch_bounds__(256) void k_node_mfma(
    const float* __restrict__ x, const u16* __restrict__ wf, const float* __restrict__ bias,
    const float* __restrict__ g, const float* __restrict__ bb, const float* __restrict__ m,
    const float* __restrict__ v, u16* __restrict__ h, int N) {
    int wv = threadIdx.x >> 6, lane = threadIdx.x & 63;
    int rowbase = blockIdx.x * 64 + wv * 16;
    if (rowbase >= N) return;
    int n16 = lane & 15, quad = lane >> 4;
    int arow = min(rowbase + n16, N - 1);
    f32x4 acc[8] = {};
    #pragma unroll
    for (int kt = 0; kt < 2; kt++) {
        bf16x8 a = pack8(x + (size_t)arow * FD + kt * 32 + quad * 8);
        #pragma unroll
        for (int ct = 0; ct < 8; ct++) {
            bf16x8 b = *(const bf16x8*)(wf + ((size_t)(ct * 2 + kt) * 64 + lane) * 8);
            acc[ct] = __builtin_amdgcn_mfma_f32_16x16x32_bf16(a, b, acc[ct], 0, 0, 0);
        }
    }
    #pragma unroll
    for (int ct = 0; ct < 8; ct++) {
        int col = ct * 16 + n16;
        float sc = g[col] * rsqrtf(v[col] + EPS);
        float bi = (bias[col] - m[col]) * sc + bb[col];
        #pragma unroll
        for (int reg = 0; reg < 4; reg++) {
            int row = rowbase + quad * 4 + reg;
            if (row < N) h[(size_t)row * HD + col] = f2b(fmaxf(acc[ct][reg] * sc + bi, 0.f));
        }
    }
}

// ---------------- GAT linear via MFMA: hh = h @ lin; a_src/a_dst fused ----------------
__global__ __launch_bounds__(256) void k_gat_mfma(
    const u16* __restrict__ h, const u16* __restrict__ wf,
    const float* __restrict__ asrcw, const float* __restrict__ adstw,
    u16* __restrict__ hh, float* __restrict__ a_src, float* __restrict__ a_dst, int N) {
    int wv = threadIdx.x >> 6, lane = threadIdx.x & 63;
    int rowbase = blockIdx.x * 64 + wv * 16;
    if (rowbase >= N) return;
    int n16 = lane & 15, quad = lane >> 4;
    int arow = min(rowbase + n16, N - 1);
    f32x4 acc[8] = {};
    #pragma unroll
    for (int kt = 0; kt < 4; kt++) {
        bf16x8 a = *(const bf16x8*)(h + (size_t)arow * HD + kt * 32 + quad * 8);
        #pragma unroll
        for (int ct = 0; ct < 8; ct++) {
            bf16x8 b = *(const bf16x8*)(wf + ((size_t)(ct * 4 + kt) * 64 + lane) * 8);
            acc[ct] = __builtin_amdgcn_mfma_f32_16x16x32_bf16(a, b, acc[ct], 0, 0, 0);
        }
    }
    // attention dots: a_src[n,hd] = sum_{c in head hd} hh[n,c]*asrcw[c]
    float asw[8], adw[8];
    #pragma unroll
    for (int ct = 0; ct < 8; ct++) {
        asw[ct] = asrcw[ct * 16 + n16];
        adw[ct] = adstw[ct * 16 + n16];
    }
    float ps[4][4], pd[4][4];
    #pragma unroll
    for (int hd = 0; hd < 4; hd++)
        #pragma unroll
        for (int reg = 0; reg < 4; reg++) {
            ps[hd][reg] = acc[2 * hd][reg] * asw[2 * hd] + acc[2 * hd + 1][reg] * asw[2 * hd + 1];
            pd[hd][reg] = acc[2 * hd][reg] * adw[2 * hd] + acc[2 * hd + 1][reg] * adw[2 * hd + 1];
        }
    #pragma unroll
    for (int msk = 1; msk < 16; msk <<= 1) {
        #pragma unroll
        for (int hd = 0; hd < 4; hd++)
            #pragma unroll
            for (int reg = 0; reg < 4; reg++) {
                ps[hd][reg] += __shfl_xor(ps[hd][reg], msk);
                pd[hd][reg] += __shfl_xor(pd[hd][reg], msk);
            }
    }
    #pragma unroll
    for (int reg = 0; reg < 4; reg++) {
        int row = rowbase + quad * 4 + reg;
        if (row < N) {
            #pragma unroll
            for (int ct = 0; ct < 8; ct++)
                hh[(size_t)row * HD + ct * 16 + n16] = f2b(acc[ct][reg]);
            if (n16 < 4) {
                float ws = 0.f, wd = 0.f;
                #pragma unroll
                for (int hd = 0; hd < 4; hd++)
                    if (n16 == hd) { ws = ps[hd][reg]; wd = pd[hd][reg]; }
                a_src[row * 4 + n16] = ws;
                a_dst[row * 4 + n16] = wd;
            }
        }
    }
}

// ---------------- per-node attention aggregation: batched two-phase gather ----------------
__global__ __launch_bounds__(256) void k_agg(
    u16* __restrict__ h, const u32* __restrict__ hh32,
    const float* __restrict__ a_src, const float* __restrict__ a_dst,
    const int* __restrict__ rowptr, const int* __restrict__ colidx,
    const float* __restrict__ bias, const float* __restrict__ bng, const float* __restrict__ bnb,
    const float* __restrict__ bnm, const float* __restrict__ bnv, int N) {
    __shared__ int   sL[4][64];
    __shared__ __align__(16) float eeL[4][64][4];
    int wv = threadIdx.x >> 6, lane = threadIdx.x & 63;
    int node = blockIdx.x * 4 + wv;
    if (node >= N) return;   // whole-wave exit; no cross-wave sync in this kernel
    int head = lane >> 4;
    const float4* as4p = (const float4*)a_src;
    float4 ad4 = ((const float4*)a_dst)[node];
    float adh = (head == 0) ? ad4.x : (head == 1) ? ad4.y : (head == 2) ? ad4.z : ad4.w;
    float ash = a_src[node * 4 + head];
    // self loop
    float e = ash + adh;
    e = (e > 0.f) ? e : 0.2f * e;
    float ee = __expf(e);
    float den = ee;
    u32 hv = hh32[(size_t)node * 64 + lane];
    float acc0 = ee * lo16(hv), acc1 = ee * hi16(hv);
    int beg = rowptr[node], end = rowptr[node + 1];
    for (int base = beg; base < end; base += 64) {
        int cnt = end - base; if (cnt > 64) cnt = 64;
        // phase 1: parallel edge loads + exp for all 4 heads
        int s = 0;
        float4 e4 = {0.f, 0.f, 0.f, 0.f};
        if (lane < cnt) {
            s = colidx[base + lane];
            float4 as4 = as4p[s];
            float t0 = as4.x + ad4.x, t1 = as4.y + ad4.y, t2 = as4.z + ad4.z, t3 = as4.w + ad4.w;
            t0 = (t0 > 0.f) ? t0 : 0.2f * t0; t1 = (t1 > 0.f) ? t1 : 0.2f * t1;
            t2 = (t2 > 0.f) ? t2 : 0.2f * t2; t3 = (t3 > 0.f) ? t3 : 0.2f * t3;
            e4.x = __expf(t0); e4.y = __expf(t1); e4.z = __expf(t2); e4.w = __expf(t3);
        }
        sL[wv][lane] = s;
        ((float4*)eeL[wv][lane])[0] = e4;   // same-wave producer/consumer; compiler inserts lgkmcnt
        // phase 2: independent coalesced hh gathers
        #pragma unroll 4
        for (int j = 0; j < cnt; j++) {
            int sj = sL[wv][j];
            float w = eeL[wv][j][head];
            u32 hv2 = hh32[(size_t)sj * 64 + lane];
            den += w;
            acc0 += w * lo16(hv2);
            acc1 += w * hi16(hv2);
        }
    }
    float inv = 1.0f / (den + 1e-16f);
    int c0 = lane * 2, c1 = c0 + 1;
    float o0 = acc0 * inv, o1 = acc1 * inv;
    float sc0 = bng[c0] * rsqrtf(bnv[c0] + EPS);
    float sc1 = bng[c1] * rsqrtf(bnv[c1] + EPS);
    o0 = (o0 + bias[c0] - bnm[c0]) * sc0 + bnb[c0];
    o1 = (o1 + bias[c1] - bnm[c1]) * sc1 + bnb[c1];
    o0 = fmaxf(o0, 0.f); o1 = fmaxf(o1, 0.f);
    u32 idv = ((const u32*)h)[(size_t)node * 64 + lane];  // residual identity
    o0 += lo16(idv); o1 += hi16(idv);
    ((u32*)h)[(size_t)node * 64 + lane] = ((u32)f2b(o1) << 16) | f2b(o0);
}

// ---------------- per-graph mean/max pooling (256 thr, 2-way row split) ----------------
__global__ __launch_bounds__(256) void k_pool(
    const u16* __restrict__ h, const int* __restrict__ batch,
    float* __restrict__ z, int N, int G) {
    __shared__ float ssum[128], smax[128];
    int g = blockIdx.x;
    int c = threadIdx.x & 127, half = threadIdx.x >> 7;
    int lo = 0, hi = N;
    while (lo < hi) { int mid = (lo + hi) >> 1; if (batch[mid] < g) lo = mid + 1; else hi = mid; }
    int beg = lo;
    hi = N;
    while (lo < hi) { int mid = (lo + hi) >> 1; if (batch[mid] <= g) lo = mid + 1; else hi = mid; }
    int end = lo;
    float s = 0.f, mx = -3.4e38f;
    for (int r = beg + half; r < end; r += 2) {
        float v = b2f(h[(size_t)r * HD + c]);
        s += v; mx = fmaxf(mx, v);
    }
    if (half == 1) { ssum[c] = s; smax[c] = mx; }
    __syncthreads();
    if (half == 0) {
        s += ssum[c]; mx = fmaxf(mx, smax[c]);
        int cnt = end - beg;
        float mean = s / (float)(cnt > 0 ? cnt : 1);
        if (cnt == 0) mx = 0.f;
        z[(size_t)g * 384 + c] = mean;
        z[(size_t)g * 384 + 128 + c] = mx;
    }
}

// ---------------- global-feature encoder ----------------
__global__ __launch_bounds__(128) void k_glob(
    const float* __restrict__ gf, const float* __restrict__ W, const float* __restrict__ b,
    const float* __restrict__ g_, const float* __restrict__ bb, const float* __restrict__ m_,
    const float* __restrict__ v_, float* __restrict__ z, int G) {
    int g = blockIdx.x, j = threadIdx.x;
    float acc = b[j];
    #pragma unroll 8
    for (int k = 0; k < 32; k++) acc += gf[g * 32 + k] * W[k * HD + j];
    float sc = g_[j] * rsqrtf(v_[j] + EPS);
    acc = (acc - m_[j]) * sc + bb[j];
    z[(size_t)g * 384 + 256 + j] = fmaxf(acc, 0.f);
}

// ---------------- final head: relu(z @ W1 + b1) @ W2 + b2 ----------------
__global__ __launch_bounds__(128) void k_final(
    const float* __restrict__ z, const float* __restrict__ W1, const float* __restrict__ b1,
    const float* __restrict__ W2, const float* __restrict__ b2, float* __restrict__ out, int G) {
    __shared__ float zs[384];
    __shared__ float red[128];
    int g = blockIdx.x, tid = threadIdx.x;
    for (int i = tid; i < 384; i += 128) zs[i] = z[(size_t)g * 384 + i];
    __syncthreads();
    float acc = b1[tid];
    #pragma unroll 4
    for (int k = 0; k < 384; k++) acc += zs[k] * W1[k * HD + tid];
    acc = fmaxf(acc, 0.f);
    red[tid] = acc * W2[tid];
    __syncthreads();
    for (int sft = 64; sft > 0; sft >>= 1) {
        if (tid < sft) red[tid] += red[tid + sft];
        __syncthreads();
    }
    if (tid == 0) out[g] = red[0] + b2[0];
}

extern "C" void kernel_launch(void* const* d_in, const int* in_sizes, int n_in,
                              void* d_out, int out_size, void* d_ws, size_t ws_size,
                              hipStream_t stream) {
    (void)n_in; (void)out_size; (void)ws_size;
    const float* x        = (const float*)d_in[0];
    const float* gfeat    = (const float*)d_in[2];
    const int*   ei       = (const int*)d_in[3];
    const int*   batch    = (const int*)d_in[4];
    const float* node_w   = (const float*)d_in[5];
    const float* node_b   = (const float*)d_in[6];
    const float* nbg      = (const float*)d_in[7];
    const float* nbb      = (const float*)d_in[8];
    const float* nbm      = (const float*)d_in[9];
    const float* nbv      = (const float*)d_in[10];
    const float* glob_w   = (const float*)d_in[13];
    const float* glob_b   = (const float*)d_in[14];
    const float* gbg      = (const float*)d_in[15];
    const float* gbb      = (const float*)d_in[16];
    const float* gbm      = (const float*)d_in[17];
    const float* gbv      = (const float*)d_in[18];
    const float* gat_lin  = (const float*)d_in[19];
    const float* gat_asrc = (const float*)d_in[20];
    const float* gat_adst = (const float*)d_in[21];
    const float* gat_bias = (const float*)d_in[22];
    const float* bn_g     = (const float*)d_in[23];
    const float* bn_b     = (const float*)d_in[24];
    const float* bn_m     = (const float*)d_in[25];
    const float* bn_v     = (const float*)d_in[26];
    const float* lin1_w   = (const float*)d_in[27];
    const float* lin1_b   = (const float*)d_in[28];
    const float* lin2_w   = (const float*)d_in[29];
    const float* lin2_b   = (const float*)d_in[30];

    const int N = in_sizes[0] / FD;
    const int E = in_sizes[3] / 2;
    const int G = in_sizes[2] / 32;
    const int* srcp = ei;
    const int* dstp = ei + E;

    char* p = (char*)d_ws;
    auto alloc = [&](size_t bytes) -> char* {
        char* r = p;
        p += (bytes + 255) & ~(size_t)255;
        return r;
    };
    u16*   h       = (u16*)alloc((size_t)N * HD * 2);
    u16*   hh      = (u16*)alloc((size_t)N * HD * 2);
    float* a_src   = (float*)alloc((size_t)N * 4 * 4);
    float* a_dst   = (float*)alloc((size_t)N * 4 * 4);
    int*   rowptr  = (int*)alloc((size_t)(N + 1) * 4);
    int*   cnt     = (int*)alloc((size_t)N * 4);
    int*   fill    = (int*)alloc((size_t)N * 4);
    int*   bsum    = (int*)alloc(256 * 4);
    int*   colidx  = (int*)alloc((size_t)E * 4);
    float* z       = (float*)alloc((size_t)G * 384 * 4);
    u16*   wf_node = (u16*)alloc((size_t)FD * HD * 2);
    u16*   wf_gat  = (u16*)alloc((size_t)3 * HD * HD * 2);

    hipMemsetAsync(cnt, 0, (size_t)N * 4, stream);
    hipMemsetAsync(fill, 0, (size_t)N * 4, stream);

    k_wprep<<<dim3(32, 4), 256, 0, stream>>>(node_w, gat_lin, wf_node, wf_gat);

    int eb = (E + 255) / 256;
    int SB = (N + 255) / 256;  // 196 <= 256, single-block second-level scan OK
    k_hist<<<eb, 256, 0, stream>>>(dstp, cnt, E);
    k_scanA<<<SB, 256, 0, stream>>>(cnt, rowptr, bsum, N);
    k_scanB<<<1, 256, 0, stream>>>(bsum, SB);
    k_scanC<<<SB, 256, 0, stream>>>(rowptr, bsum, N);
    k_scatter<<<eb, 256, 0, stream>>>(srcp, dstp, rowptr, fill, colidx, E);

    k_node_mfma<<<(N + 63) / 64, 256, 0, stream>>>(x, wf_node, node_b, nbg, nbb, nbm, nbv, h, N);

    for (int i = 0; i < 3; i++) {
        k_gat_mfma<<<(N + 63) / 64, 256, 0, stream>>>(
            h, wf_gat + (size_t)i * HD * HD,
            gat_asrc + i * HD, gat_adst + i * HD,
            hh, a_src, a_dst, N);
        k_agg<<<(N + 3) / 4, 256, 0, stream>>>(
            h, (const u32*)hh, a_src, a_dst, rowptr, colidx,
            gat_bias + i * HD, bn_g + i * HD, bn_b + i * HD, bn_m + i * HD, bn_v + i * HD, N);
    }

    k_pool<<<G, 256, 0, stream>>>(h, batch, z, N, G);
    k_glob<<<G, 128, 0, stream>>>(gfeat, glob_w, glob_b, gbg, gbb, gbm, gbv, z, G);
    k_final<<<G, 128, 0, stream>>>(z, lin1_w, lin1_b, lin2_w, lin2_b, (float*)d_out, G);
}

// Round 5
// 436.842 us; speedup vs baseline: 1.7776x; 1.0643x over previous
//
#include <hip/hip_runtime.h>
#include <hip/hip_bf16.h>

typedef unsigned short u16;
typedef unsigned int   u32;
typedef unsigned long long u64;

// N=50000, F=64, H=128, HEADS=4, C=32, L=3, E=800000, G=512, DG=32, NC=1
// Float inputs/outputs are FLOAT32; internal node features h/hh are bf16 for MFMA.
#define HD 128
#define FD 64
#define EPS 1e-5f

using bf16x8 = __attribute__((ext_vector_type(8))) short;
using f32x4  = __attribute__((ext_vector_type(4))) float;

__device__ __forceinline__ float b2f(u16 v) { return __uint_as_float(((u32)v) << 16); }
__device__ __forceinline__ u16 f2b(float f) {
    u32 u = __float_as_uint(f);
    return (u16)((u + 0x7FFF + ((u >> 16) & 1)) >> 16);  // RNE
}
__device__ __forceinline__ float lo16(u32 u) { return __uint_as_float(u << 16); }
__device__ __forceinline__ float hi16(u32 u) { return __uint_as_float(u & 0xFFFF0000u); }

__device__ __forceinline__ bf16x8 pack8(const float* p) {
    bf16x8 r;
    #pragma unroll
    for (int j = 0; j < 8; j++) r[j] = (short)f2b(p[j]);
    return r;
}

// ---------------- CSR build: per-node histogram ----------------
__global__ __launch_bounds__(256) void k_hist(const int* __restrict__ dst, int* __restrict__ cnt, int E) {
    int e = blockIdx.x * 256 + threadIdx.x;
    if (e < E) atomicAdd(&cnt[dst[e]], 1);
}

__global__ __launch_bounds__(256) void k_scanA(const int* __restrict__ cnt, int* __restrict__ rowptr,
                                               int* __restrict__ bsum, int N) {
    __shared__ int s[256];
    int tid = threadIdx.x;
    int i = blockIdx.x * 256 + tid;
    s[tid] = (i < N) ? cnt[i] : 0;
    __syncthreads();
    for (int off = 1; off < 256; off <<= 1) {
        int t = (tid >= off) ? s[tid - off] : 0;
        __syncthreads();
        s[tid] += t;
        __syncthreads();
    }
    if (i < N) rowptr[i + 1] = s[tid];
    if (tid == 255) bsum[blockIdx.x] = s[255];
}

__global__ __launch_bounds__(256) void k_scanB(int* __restrict__ bsum, int SB) {
    __shared__ int s[256];
    int tid = threadIdx.x;
    s[tid] = (tid < SB) ? bsum[tid] : 0;
    __syncthreads();
    for (int off = 1; off < 256; off <<= 1) {
        int t = (tid >= off) ? s[tid - off] : 0;
        __syncthreads();
        s[tid] += t;
        __syncthreads();
    }
    if (tid < SB) bsum[tid] = s[tid];
}

__global__ __launch_bounds__(256) void k_scanC(int* __restrict__ rowptr, const int* __restrict__ bsum, int N) {
    int i = blockIdx.x * 256 + threadIdx.x;
    if (i == 0) rowptr[0] = 0;
    if (i < N) {
        int b = i >> 8;
        if (b > 0) rowptr[i + 1] += bsum[b - 1];
    }
}

// ---------------- binned scatter, pass A: tile counting-sort by bucket ----------------
// Tile = 4096 edges staged in registers (16/thread); sorted runs written bucket-contiguously.
__global__ __launch_bounds__(256) void k_binA(
    const int* __restrict__ src, const int* __restrict__ dst, const int* __restrict__ rowptr,
    int* __restrict__ bcur, u64* __restrict__ binned, int E, int bsh, int NB, int numTiles) {
    __shared__ u32 os[4096], od[4096];           // 32 KB sorted tile
    __shared__ int hist[256], obase[256], ofs[256], gpos[256];
    int tid = threadIdx.x;
    for (int t = blockIdx.x; t < numTiles; t += gridDim.x) {
        int base = t * 4096;
        int cnt = E - base; if (cnt > 4096) cnt = 4096;
        hist[tid] = 0;
        __syncthreads();
        u32 rs[16], rd[16];
        #pragma unroll
        for (int r = 0; r < 16; r++) {
            int li = r * 256 + tid;
            if (li < cnt) {
                rs[r] = src[base + li];
                rd[r] = dst[base + li];
                atomicAdd(&hist[rd[r] >> bsh], 1);
            }
        }
        __syncthreads();
        // inclusive Hillis-Steele scan of hist into obase
        int val = hist[tid];
        obase[tid] = val;
        __syncthreads();
        for (int off = 1; off < 256; off <<= 1) {
            int t2 = (tid >= off) ? obase[tid - off] : 0;
            __syncthreads();
            obase[tid] += t2;
            __syncthreads();
        }
        int excl = obase[tid] - val;
        __syncthreads();
        obase[tid] = excl;
        ofs[tid] = excl;
        __syncthreads();
        // scatter registers -> sorted LDS
        #pragma unroll
        for (int r = 0; r < 16; r++) {
            int li = r * 256 + tid;
            if (li < cnt) {
                int b = rd[r] >> bsh;
                int posn = atomicAdd(&ofs[b], 1);
                os[posn] = rs[r];
                od[posn] = rd[r];
            }
        }
        __syncthreads();
        // claim global space per bucket
        if (tid < NB && hist[tid] > 0)
            gpos[tid] = rowptr[tid << bsh] + atomicAdd(&bcur[tid], hist[tid]);
        __syncthreads();
        // copy out: consecutive li within a run -> consecutive global addresses
        for (int li = tid; li < cnt; li += 256) {
            u32 d = od[li];
            int b = d >> bsh;
            binned[(size_t)gpos[b] + (li - obase[b])] = ((u64)d << 32) | os[li];
        }
        __syncthreads();
    }
}

// ---------------- binned scatter, pass B: one block per bucket (single writer per window) ----
__global__ __launch_bounds__(256) void k_binB(
    const u64* __restrict__ binned, const int* __restrict__ rowptr,
    int* __restrict__ fill, int* __restrict__ colidx, int N, int bsh) {
    int b = blockIdx.x;
    int n0 = b << bsh;
    int n1 = (b + 1) << bsh; if (n1 > N) n1 = N;
    int r0 = rowptr[n0], r1 = rowptr[n1];
    for (int i = r0 + threadIdx.x; i < r1; i += 256) {
        u64 pk = binned[i];
        u32 d = (u32)(pk >> 32), s = (u32)pk;
        int slot = atomicAdd(&fill[d], 1);
        colidx[rowptr[d] + slot] = (int)s;
    }
}

// ---------------- weight fragment prep (f32 -> bf16 MFMA B-operand) ----------------
// frag f = ((ct*KT + kt)*64 + lane)*8 + j  holds  W[kt*32 + (lane>>4)*8 + j][ct*16 + (lane&15)]
__global__ __launch_bounds__(256) void k_wprep(const float* __restrict__ node_w, const float* __restrict__ gat_lin,
                                               u16* __restrict__ wf_node, u16* __restrict__ wf_gat) {
    int y = blockIdx.y;
    const float* src; u16* dst; int K;
    if (y == 0) { src = node_w; dst = wf_node; K = FD; }
    else { src = gat_lin + (size_t)(y - 1) * HD * HD; dst = wf_gat + (size_t)(y - 1) * HD * HD; K = HD; }
    int KT = K >> 5;
    int total = K * HD;
    for (int f = blockIdx.x * 256 + threadIdx.x; f < total; f += gridDim.x * 256) {
        int j = f & 7;
        int lane = (f >> 3) & 63;
        int t = f >> 9;           // ct*KT + kt
        int kt = t % KT;
        int ct = t / KT;
        int k = kt * 32 + (lane >> 4) * 8 + j;
        int col = ct * 16 + (lane & 15);
        dst[f] = f2b(src[k * HD + col]);
    }
}

// ---------------- node encoder via MFMA: h = relu(bn(x @ W + b)) ----------------
__global__ __launch_bounds__(256) void k_node_mfma(
    const float* __restrict__ x, const u16* __restrict__ wf, const float* __restrict__ bias,
    const float* __restrict__ g, const float* __restrict__ bb, const float* __restrict__ m,
    const float* __restrict__ v, u16* __restrict__ h, int N) {
    int wv = threadIdx.x >> 6, lane = threadIdx.x & 63;
    int rowbase = blockIdx.x * 64 + wv * 16;
    if (rowbase >= N) return;
    int n16 = lane & 15, quad = lane >> 4;
    int arow = min(rowbase + n16, N - 1);
    f32x4 acc[8] = {};
    #pragma unroll
    for (int kt = 0; kt < 2; kt++) {
        bf16x8 a = pack8(x + (size_t)arow * FD + kt * 32 + quad * 8);
        #pragma unroll
        for (int ct = 0; ct < 8; ct++) {
            bf16x8 b = *(const bf16x8*)(wf + ((size_t)(ct * 2 + kt) * 64 + lane) * 8);
            acc[ct] = __builtin_amdgcn_mfma_f32_16x16x32_bf16(a, b, acc[ct], 0, 0, 0);
        }
    }
    #pragma unroll
    for (int ct = 0; ct < 8; ct++) {
        int col = ct * 16 + n16;
        float sc = g[col] * rsqrtf(v[col] + EPS);
        float bi = (bias[col] - m[col]) * sc + bb[col];
        #pragma unroll
        for (int reg = 0; reg < 4; reg++) {
            int row = rowbase + quad * 4 + reg;
            if (row < N) h[(size_t)row * HD + col] = f2b(fmaxf(acc[ct][reg] * sc + bi, 0.f));
        }
    }
}

// ---------------- GAT linear via MFMA: hh = h @ lin; a_src/a_dst fused ----------------
__global__ __launch_bounds__(256) void k_gat_mfma(
    const u16* __restrict__ h, const u16* __restrict__ wf,
    const float* __restrict__ asrcw, const float* __restrict__ adstw,
    u16* __restrict__ hh, float* __restrict__ a_src, float* __restrict__ a_dst, int N) {
    int wv = threadIdx.x >> 6, lane = threadIdx.x & 63;
    int rowbase = blockIdx.x * 64 + wv * 16;
    if (rowbase >= N) return;
    int n16 = lane & 15, quad = lane >> 4;
    int arow = min(rowbase + n16, N - 1);
    f32x4 acc[8] = {};
    #pragma unroll
    for (int kt = 0; kt < 4; kt++) {
        bf16x8 a = *(const bf16x8*)(h + (size_t)arow * HD + kt * 32 + quad * 8);
        #pragma unroll
        for (int ct = 0; ct < 8; ct++) {
            bf16x8 b = *(const bf16x8*)(wf + ((size_t)(ct * 4 + kt) * 64 + lane) * 8);
            acc[ct] = __builtin_amdgcn_mfma_f32_16x16x32_bf16(a, b, acc[ct], 0, 0, 0);
        }
    }
    float asw[8], adw[8];
    #pragma unroll
    for (int ct = 0; ct < 8; ct++) {
        asw[ct] = asrcw[ct * 16 + n16];
        adw[ct] = adstw[ct * 16 + n16];
    }
    float ps[4][4], pd[4][4];
    #pragma unroll
    for (int hd = 0; hd < 4; hd++)
        #pragma unroll
        for (int reg = 0; reg < 4; reg++) {
            ps[hd][reg] = acc[2 * hd][reg] * asw[2 * hd] + acc[2 * hd + 1][reg] * asw[2 * hd + 1];
            pd[hd][reg] = acc[2 * hd][reg] * adw[2 * hd] + acc[2 * hd + 1][reg] * adw[2 * hd + 1];
        }
    #pragma unroll
    for (int msk = 1; msk < 16; msk <<= 1) {
        #pragma unroll
        for (int hd = 0; hd < 4; hd++)
            #pragma unroll
            for (int reg = 0; reg < 4; reg++) {
                ps[hd][reg] += __shfl_xor(ps[hd][reg], msk);
                pd[hd][reg] += __shfl_xor(pd[hd][reg], msk);
            }
    }
    #pragma unroll
    for (int reg = 0; reg < 4; reg++) {
        int row = rowbase + quad * 4 + reg;
        if (row < N) {
            #pragma unroll
            for (int ct = 0; ct < 8; ct++)
                hh[(size_t)row * HD + ct * 16 + n16] = f2b(acc[ct][reg]);
            if (n16 < 4) {
                float ws = 0.f, wd = 0.f;
                #pragma unroll
                for (int hd = 0; hd < 4; hd++)
                    if (n16 == hd) { ws = ps[hd][reg]; wd = pd[hd][reg]; }
                a_src[row * 4 + n16] = ws;
                a_dst[row * 4 + n16] = wd;
            }
        }
    }
}

// ---------------- per-node attention aggregation: batched two-phase gather ----------------
__global__ __launch_bounds__(256) void k_agg(
    u16* __restrict__ h, const u32* __restrict__ hh32,
    const float* __restrict__ a_src, const float* __restrict__ a_dst,
    const int* __restrict__ rowptr, const int* __restrict__ colidx,
    const float* __restrict__ bias, const float* __restrict__ bng, const float* __restrict__ bnb,
    const float* __restrict__ bnm, const float* __restrict__ bnv, int N) {
    __shared__ int   sL[4][64];
    __shared__ __align__(16) float eeL[4][64][4];
    int wv = threadIdx.x >> 6, lane = threadIdx.x & 63;
    int node = blockIdx.x * 4 + wv;
    if (node >= N) return;   // whole-wave exit; no cross-wave sync in this kernel
    int head = lane >> 4;
    const float4* as4p = (const float4*)a_src;
    float4 ad4 = ((const float4*)a_dst)[node];
    float adh = (head == 0) ? ad4.x : (head == 1) ? ad4.y : (head == 2) ? ad4.z : ad4.w;
    float ash = a_src[node * 4 + head];
    float e = ash + adh;
    e = (e > 0.f) ? e : 0.2f * e;
    float ee = __expf(e);
    float den = ee;
    u32 hv = hh32[(size_t)node * 64 + lane];
    float acc0 = ee * lo16(hv), acc1 = ee * hi16(hv);
    int beg = rowptr[node], end = rowptr[node + 1];
    for (int base = beg; base < end; base += 64) {
        int cnt = end - base; if (cnt > 64) cnt = 64;
        int s = 0;
        float4 e4 = {0.f, 0.f, 0.f, 0.f};
        if (lane < cnt) {
            s = colidx[base + lane];
            float4 as4 = as4p[s];
            float t0 = as4.x + ad4.x, t1 = as4.y + ad4.y, t2 = as4.z + ad4.z, t3 = as4.w + ad4.w;
            t0 = (t0 > 0.f) ? t0 : 0.2f * t0; t1 = (t1 > 0.f) ? t1 : 0.2f * t1;
            t2 = (t2 > 0.f) ? t2 : 0.2f * t2; t3 = (t3 > 0.f) ? t3 : 0.2f * t3;
            e4.x = __expf(t0); e4.y = __expf(t1); e4.z = __expf(t2); e4.w = __expf(t3);
        }
        sL[wv][lane] = s;
        ((float4*)eeL[wv][lane])[0] = e4;   // same-wave producer/consumer
        #pragma unroll 4
        for (int j = 0; j < cnt; j++) {
            int sj = sL[wv][j];
            float w = eeL[wv][j][head];
            u32 hv2 = hh32[(size_t)sj * 64 + lane];
            den += w;
            acc0 += w * lo16(hv2);
            acc1 += w * hi16(hv2);
        }
    }
    float inv = 1.0f / (den + 1e-16f);
    int c0 = lane * 2, c1 = c0 + 1;
    float o0 = acc0 * inv, o1 = acc1 * inv;
    float sc0 = bng[c0] * rsqrtf(bnv[c0] + EPS);
    float sc1 = bng[c1] * rsqrtf(bnv[c1] + EPS);
    o0 = (o0 + bias[c0] - bnm[c0]) * sc0 + bnb[c0];
    o1 = (o1 + bias[c1] - bnm[c1]) * sc1 + bnb[c1];
    o0 = fmaxf(o0, 0.f); o1 = fmaxf(o1, 0.f);
    u32 idv = ((const u32*)h)[(size_t)node * 64 + lane];  // residual identity
    o0 += lo16(idv); o1 += hi16(idv);
    ((u32*)h)[(size_t)node * 64 + lane] = ((u32)f2b(o1) << 16) | f2b(o0);
}

// ---------------- fused readout: pool (mean/max) + glob encoder + lin1 + lin2 ----------------
__global__ __launch_bounds__(256) void k_readout(
    const u16* __restrict__ h, const int* __restrict__ batch,
    const float* __restrict__ gf, const float* __restrict__ glob_w, const float* __restrict__ glob_b,
    const float* __restrict__ gbg, const float* __restrict__ gbb,
    const float* __restrict__ gbm, const float* __restrict__ gbv,
    const float* __restrict__ W1, const float* __restrict__ b1,
    const float* __restrict__ W2, const float* __restrict__ b2,
    float* __restrict__ out, int N, int G) {
    __shared__ float zs[384];
    __shared__ float sA[128], sB[128];
    __shared__ float pr[256];
    int g = blockIdx.x, tid = threadIdx.x;
    int c = tid & 127, half = tid >> 7;
    // binary search graph's node range in sorted batch
    int lo = 0, hi = N;
    while (lo < hi) { int mid = (lo + hi) >> 1; if (batch[mid] < g) lo = mid + 1; else hi = mid; }
    int beg = lo;
    hi = N;
    while (lo < hi) { int mid = (lo + hi) >> 1; if (batch[mid] <= g) lo = mid + 1; else hi = mid; }
    int end = lo;
    float s = 0.f, mx = -3.4e38f;
    for (int r = beg + half; r < end; r += 2) {
        float v = b2f(h[(size_t)r * HD + c]);
        s += v; mx = fmaxf(mx, v);
    }
    if (half == 1) { sA[c] = s; sB[c] = mx; }
    __syncthreads();
    if (half == 0) {
        s += sA[c]; mx = fmaxf(mx, sB[c]);
        int cntn = end - beg;
        zs[c] = s / (float)(cntn > 0 ? cntn : 1);
        zs[128 + c] = (cntn == 0) ? 0.f : mx;
    } else {
        float acc = glob_b[c];
        #pragma unroll 8
        for (int k = 0; k < 32; k++) acc += gf[g * 32 + k] * glob_w[k * HD + c];
        float sc = gbg[c] * rsqrtf(gbv[c] + EPS);
        acc = (acc - gbm[c]) * sc + gbb[c];
        zs[256 + c] = fmaxf(acc, 0.f);
    }
    __syncthreads();
    // lin1 with 2-way K split
    float acc = (half == 0) ? b1[c] : 0.f;
    int k0 = half * 192;
    #pragma unroll 4
    for (int k = k0; k < k0 + 192; k++) acc += zs[k] * W1[k * HD + c];
    pr[tid] = acc;
    __syncthreads();
    if (half == 0) {
        float a = fmaxf(pr[c] + pr[c + 128], 0.f);
        pr[c] = a * W2[c];
    }
    __syncthreads();
    for (int sft = 64; sft > 0; sft >>= 1) {
        if (tid < sft) pr[tid] += pr[tid + sft];
        __syncthreads();
    }
    if (tid == 0) out[g] = pr[0] + b2[0];
}

extern "C" void kernel_launch(void* const* d_in, const int* in_sizes, int n_in,
                              void* d_out, int out_size, void* d_ws, size_t ws_size,
                              hipStream_t stream) {
    (void)n_in; (void)out_size; (void)ws_size;
    const float* x        = (const float*)d_in[0];
    const float* gfeat    = (const float*)d_in[2];
    const int*   ei       = (const int*)d_in[3];
    const int*   batch    = (const int*)d_in[4];
    const float* node_w   = (const float*)d_in[5];
    const float* node_b   = (const float*)d_in[6];
    const float* nbg      = (const float*)d_in[7];
    const float* nbb      = (const float*)d_in[8];
    const float* nbm      = (const float*)d_in[9];
    const float* nbv      = (const float*)d_in[10];
    const float* glob_w   = (const float*)d_in[13];
    const float* glob_b   = (const float*)d_in[14];
    const float* gbg      = (const float*)d_in[15];
    const float* gbb      = (const float*)d_in[16];
    const float* gbm      = (const float*)d_in[17];
    const float* gbv      = (const float*)d_in[18];
    const float* gat_lin  = (const float*)d_in[19];
    const float* gat_asrc = (const float*)d_in[20];
    const float* gat_adst = (const float*)d_in[21];
    const float* gat_bias = (const float*)d_in[22];
    const float* bn_g     = (const float*)d_in[23];
    const float* bn_b     = (const float*)d_in[24];
    const float* bn_m     = (const float*)d_in[25];
    const float* bn_v     = (const float*)d_in[26];
    const float* lin1_w   = (const float*)d_in[27];
    const float* lin1_b   = (const float*)d_in[28];
    const float* lin2_w   = (const float*)d_in[29];
    const float* lin2_b   = (const float*)d_in[30];

    const int N = in_sizes[0] / FD;
    const int E = in_sizes[3] / 2;
    const int G = in_sizes[2] / 32;
    const int* srcp = ei;
    const int* dstp = ei + E;

    int bsh = 8;
    while (((N + (1 << bsh) - 1) >> bsh) > 256) bsh++;
    const int NB = (N + (1 << bsh) - 1) >> bsh;

    char* p = (char*)d_ws;
    auto alloc = [&](size_t bytes) -> char* {
        char* r = p;
        p += (bytes + 255) & ~(size_t)255;
        return r;
    };
    u16*   h       = (u16*)alloc((size_t)N * HD * 2);
    u16*   hh      = (u16*)alloc((size_t)N * HD * 2);
    float* a_src   = (float*)alloc((size_t)N * 4 * 4);
    float* a_dst   = (float*)alloc((size_t)N * 4 * 4);
    int*   rowptr  = (int*)alloc((size_t)(N + 1) * 4);
    // zero-init group: cnt, fill, bcur contiguous -> one memset
    char*  zbase   = p;
    int*   cnt     = (int*)alloc((size_t)N * 4);
    int*   fill    = (int*)alloc((size_t)N * 4);
    int*   bcur    = (int*)alloc(256 * 4);
    size_t zbytes  = (size_t)(p - zbase);
    int*   bsum    = (int*)alloc(256 * 4);
    int*   colidx  = (int*)alloc((size_t)E * 4);
    u64*   binned  = (u64*)alloc((size_t)E * 8);
    u16*   wf_node = (u16*)alloc((size_t)FD * HD * 2);
    u16*   wf_gat  = (u16*)alloc((size_t)3 * HD * HD * 2);

    hipMemsetAsync(zbase, 0, zbytes, stream);

    k_wprep<<<dim3(32, 4), 256, 0, stream>>>(node_w, gat_lin, wf_node, wf_gat);

    int eb = (E + 255) / 256;
    int SB = (N + 255) / 256;  // <= 256: single-block second-level scan OK
    k_hist<<<eb, 256, 0, stream>>>(dstp, cnt, E);
    k_scanA<<<SB, 256, 0, stream>>>(cnt, rowptr, bsum, N);
    k_scanB<<<1, 256, 0, stream>>>(bsum, SB);
    k_scanC<<<SB, 256, 0, stream>>>(rowptr, bsum, N);

    int numTiles = (E + 4095) / 4096;
    int binAGrid = numTiles < 512 ? numTiles : 512;
    k_binA<<<binAGrid, 256, 0, stream>>>(srcp, dstp, rowptr, bcur, binned, E, bsh, NB, numTiles);
    k_binB<<<NB, 256, 0, stream>>>(binned, rowptr, fill, colidx, N, bsh);

    k_node_mfma<<<(N + 63) / 64, 256, 0, stream>>>(x, wf_node, node_b, nbg, nbb, nbm, nbv, h, N);

    for (int i = 0; i < 3; i++) {
        k_gat_mfma<<<(N + 63) / 64, 256, 0, stream>>>(
            h, wf_gat + (size_t)i * HD * HD,
            gat_asrc + i * HD, gat_adst + i * HD,
            hh, a_src, a_dst, N);
        k_agg<<<(N + 3) / 4, 256, 0, stream>>>(
            h, (const u32*)hh, a_src, a_dst, rowptr, colidx,
            gat_bias + i * HD, bn_g + i * HD, bn_b + i * HD, bn_m + i * HD, bn_v + i * HD, N);
    }

    k_readout<<<G, 256, 0, stream>>>(h, batch, gfeat, glob_w, glob_b, gbg, gbb, gbm, gbv,
                                     lin1_w, lin1_b, lin2_w, lin2_b, (float*)d_out, N, G);
}

// Round 6
// 435.518 us; speedup vs baseline: 1.7830x; 1.0030x over previous
//
#include <hip/hip_runtime.h>
#include <hip/hip_bf16.h>

typedef unsigned short u16;
typedef unsigned int   u32;
typedef unsigned long long u64;

// N=50000, F=64, H=128, HEADS=4, C=32, L=3, E=800000, G=512, DG=32, NC=1
// Float inputs/outputs are FLOAT32; internal node features h/hh are bf16 for MFMA.
#define HD 128
#define FD 64
#define EPS 1e-5f

using bf16x8 = __attribute__((ext_vector_type(8))) short;
using f32x4  = __attribute__((ext_vector_type(4))) float;

__device__ __forceinline__ float b2f(u16 v) { return __uint_as_float(((u32)v) << 16); }
__device__ __forceinline__ u16 f2b(float f) {
    u32 u = __float_as_uint(f);
    return (u16)((u + 0x7FFF + ((u >> 16) & 1)) >> 16);  // RNE
}
__device__ __forceinline__ float lo16(u32 u) { return __uint_as_float(u << 16); }
__device__ __forceinline__ float hi16(u32 u) { return __uint_as_float(u & 0xFFFF0000u); }

__device__ __forceinline__ bf16x8 pack8(const float* p) {
    bf16x8 r;
    #pragma unroll
    for (int j = 0; j < 8; j++) r[j] = (short)f2b(p[j]);
    return r;
}

// ---------------- CSR build: per-node histogram ----------------
__global__ __launch_bounds__(256) void k_hist(const int* __restrict__ dst, int* __restrict__ cnt, int E) {
    int e = blockIdx.x * 256 + threadIdx.x;
    if (e < E) atomicAdd(&cnt[dst[e]], 1);
}

__global__ __launch_bounds__(256) void k_scanA(const int* __restrict__ cnt, int* __restrict__ rowptr,
                                               int* __restrict__ bsum, int N) {
    __shared__ int s[256];
    int tid = threadIdx.x;
    int i = blockIdx.x * 256 + tid;
    s[tid] = (i < N) ? cnt[i] : 0;
    __syncthreads();
    for (int off = 1; off < 256; off <<= 1) {
        int t = (tid >= off) ? s[tid - off] : 0;
        __syncthreads();
        s[tid] += t;
        __syncthreads();
    }
    if (i < N) rowptr[i + 1] = s[tid];
    if (tid == 255) bsum[blockIdx.x] = s[255];
}

__global__ __launch_bounds__(256) void k_scanB(int* __restrict__ bsum, int SB) {
    __shared__ int s[256];
    int tid = threadIdx.x;
    s[tid] = (tid < SB) ? bsum[tid] : 0;
    __syncthreads();
    for (int off = 1; off < 256; off <<= 1) {
        int t = (tid >= off) ? s[tid - off] : 0;
        __syncthreads();
        s[tid] += t;
        __syncthreads();
    }
    if (tid < SB) bsum[tid] = s[tid];
}

__global__ __launch_bounds__(256) void k_scanC(int* __restrict__ rowptr, const int* __restrict__ bsum, int N) {
    int i = blockIdx.x * 256 + threadIdx.x;
    if (i == 0) rowptr[0] = 0;
    if (i < N) {
        int b = i >> 8;
        if (b > 0) rowptr[i + 1] += bsum[b - 1];
    }
}

// ---------------- graph boundaries from sorted batch ----------------
__global__ __launch_bounds__(256) void k_gbound(const int* __restrict__ batch, int* __restrict__ gs, int N, int G) {
    int i = blockIdx.x * 256 + threadIdx.x;
    if (i < N) {
        int b = batch[i];
        if (i == 0) { for (int g = 0; g <= b; g++) gs[g] = 0; }
        else {
            int pb = batch[i - 1];
            for (int g = pb + 1; g <= b; g++) gs[g] = i;
        }
        if (i == N - 1) { for (int g = b + 1; g <= G; g++) gs[g] = N; }
    }
}

// ---------------- binned scatter, pass A: tile counting-sort by bucket ----------------
__global__ __launch_bounds__(256) void k_binA(
    const int* __restrict__ src, const int* __restrict__ dst, const int* __restrict__ rowptr,
    int* __restrict__ bcur, u64* __restrict__ binned, int E, int bsh, int NB, int numTiles) {
    __shared__ u32 os[4096], od[4096];           // 32 KB sorted tile
    __shared__ int hist[256], obase[256], ofs[256], gpos[256];
    int tid = threadIdx.x;
    for (int t = blockIdx.x; t < numTiles; t += gridDim.x) {
        int base = t * 4096;
        int cnt = E - base; if (cnt > 4096) cnt = 4096;
        hist[tid] = 0;
        __syncthreads();
        u32 rs[16], rd[16];
        #pragma unroll
        for (int r = 0; r < 16; r++) {
            int li = r * 256 + tid;
            if (li < cnt) {
                rs[r] = src[base + li];
                rd[r] = dst[base + li];
                atomicAdd(&hist[rd[r] >> bsh], 1);
            }
        }
        __syncthreads();
        int val = hist[tid];
        obase[tid] = val;
        __syncthreads();
        for (int off = 1; off < 256; off <<= 1) {
            int t2 = (tid >= off) ? obase[tid - off] : 0;
            __syncthreads();
            obase[tid] += t2;
            __syncthreads();
        }
        int excl = obase[tid] - val;
        __syncthreads();
        obase[tid] = excl;
        ofs[tid] = excl;
        __syncthreads();
        #pragma unroll
        for (int r = 0; r < 16; r++) {
            int li = r * 256 + tid;
            if (li < cnt) {
                int b = rd[r] >> bsh;
                int posn = atomicAdd(&ofs[b], 1);
                os[posn] = rs[r];
                od[posn] = rd[r];
            }
        }
        __syncthreads();
        if (tid < NB && hist[tid] > 0)
            gpos[tid] = rowptr[tid << bsh] + atomicAdd(&bcur[tid], hist[tid]);
        __syncthreads();
        for (int li = tid; li < cnt; li += 256) {
            u32 d = od[li];
            int b = d >> bsh;
            binned[(size_t)gpos[b] + (li - obase[b])] = ((u64)d << 32) | os[li];
        }
        __syncthreads();
    }
}

// ---------------- binned scatter, pass B: one block per bucket ----------------
__global__ __launch_bounds__(256) void k_binB(
    const u64* __restrict__ binned, const int* __restrict__ rowptr,
    int* __restrict__ fill, int* __restrict__ colidx, int N, int bsh) {
    int b = blockIdx.x;
    int n0 = b << bsh;
    int n1 = (b + 1) << bsh; if (n1 > N) n1 = N;
    int r0 = rowptr[n0], r1 = rowptr[n1];
    for (int i = r0 + threadIdx.x; i < r1; i += 256) {
        u64 pk = binned[i];
        u32 d = (u32)(pk >> 32), s = (u32)pk;
        int slot = atomicAdd(&fill[d], 1);
        colidx[rowptr[d] + slot] = (int)s;
    }
}

// ---------------- weight fragment prep (f32 -> bf16 MFMA B-operand) ----------------
__global__ __launch_bounds__(256) void k_wprep(const float* __restrict__ node_w, const float* __restrict__ gat_lin,
                                               u16* __restrict__ wf_node, u16* __restrict__ wf_gat) {
    int y = blockIdx.y;
    const float* src; u16* dst; int K;
    if (y == 0) { src = node_w; dst = wf_node; K = FD; }
    else { src = gat_lin + (size_t)(y - 1) * HD * HD; dst = wf_gat + (size_t)(y - 1) * HD * HD; K = HD; }
    int KT = K >> 5;
    int total = K * HD;
    for (int f = blockIdx.x * 256 + threadIdx.x; f < total; f += gridDim.x * 256) {
        int j = f & 7;
        int lane = (f >> 3) & 63;
        int t = f >> 9;
        int kt = t % KT;
        int ct = t / KT;
        int k = kt * 32 + (lane >> 4) * 8 + j;
        int col = ct * 16 + (lane & 15);
        dst[f] = f2b(src[k * HD + col]);
    }
}

// ---------------- node encoder via MFMA ----------------
__global__ __launch_bounds__(256) void k_node_mfma(
    const float* __restrict__ x, const u16* __restrict__ wf, const float* __restrict__ bias,
    const float* __restrict__ g, const float* __restrict__ bb, const float* __restrict__ m,
    const float* __restrict__ v, u16* __restrict__ h, int N) {
    int wv = threadIdx.x >> 6, lane = threadIdx.x & 63;
    int rowbase = blockIdx.x * 64 + wv * 16;
    if (rowbase >= N) return;
    int n16 = lane & 15, quad = lane >> 4;
    int arow = min(rowbase + n16, N - 1);
    f32x4 acc[8] = {};
    #pragma unroll
    for (int kt = 0; kt < 2; kt++) {
        bf16x8 a = pack8(x + (size_t)arow * FD + kt * 32 + quad * 8);
        #pragma unroll
        for (int ct = 0; ct < 8; ct++) {
            bf16x8 b = *(const bf16x8*)(wf + ((size_t)(ct * 2 + kt) * 64 + lane) * 8);
            acc[ct] = __builtin_amdgcn_mfma_f32_16x16x32_bf16(a, b, acc[ct], 0, 0, 0);
        }
    }
    #pragma unroll
    for (int ct = 0; ct < 8; ct++) {
        int col = ct * 16 + n16;
        float sc = g[col] * rsqrtf(v[col] + EPS);
        float bi = (bias[col] - m[col]) * sc + bb[col];
        #pragma unroll
        for (int reg = 0; reg < 4; reg++) {
            int row = rowbase + quad * 4 + reg;
            if (row < N) h[(size_t)row * HD + col] = f2b(fmaxf(acc[ct][reg] * sc + bi, 0.f));
        }
    }
}

// ---------------- GAT linear via MFMA ----------------
__global__ __launch_bounds__(256) void k_gat_mfma(
    const u16* __restrict__ h, const u16* __restrict__ wf,
    const float* __restrict__ asrcw, const float* __restrict__ adstw,
    u16* __restrict__ hh, float* __restrict__ a_src, float* __restrict__ a_dst, int N) {
    int wv = threadIdx.x >> 6, lane = threadIdx.x & 63;
    int rowbase = blockIdx.x * 64 + wv * 16;
    if (rowbase >= N) return;
    int n16 = lane & 15, quad = lane >> 4;
    int arow = min(rowbase + n16, N - 1);
    f32x4 acc[8] = {};
    #pragma unroll
    for (int kt = 0; kt < 4; kt++) {
        bf16x8 a = *(const bf16x8*)(h + (size_t)arow * HD + kt * 32 + quad * 8);
        #pragma unroll
        for (int ct = 0; ct < 8; ct++) {
            bf16x8 b = *(const bf16x8*)(wf + ((size_t)(ct * 4 + kt) * 64 + lane) * 8);
            acc[ct] = __builtin_amdgcn_mfma_f32_16x16x32_bf16(a, b, acc[ct], 0, 0, 0);
        }
    }
    float asw[8], adw[8];
    #pragma unroll
    for (int ct = 0; ct < 8; ct++) {
        asw[ct] = asrcw[ct * 16 + n16];
        adw[ct] = adstw[ct * 16 + n16];
    }
    float ps[4][4], pd[4][4];
    #pragma unroll
    for (int hd = 0; hd < 4; hd++)
        #pragma unroll
        for (int reg = 0; reg < 4; reg++) {
            ps[hd][reg] = acc[2 * hd][reg] * asw[2 * hd] + acc[2 * hd + 1][reg] * asw[2 * hd + 1];
            pd[hd][reg] = acc[2 * hd][reg] * adw[2 * hd] + acc[2 * hd + 1][reg] * adw[2 * hd + 1];
        }
    #pragma unroll
    for (int msk = 1; msk < 16; msk <<= 1) {
        #pragma unroll
        for (int hd = 0; hd < 4; hd++)
            #pragma unroll
            for (int reg = 0; reg < 4; reg++) {
                ps[hd][reg] += __shfl_xor(ps[hd][reg], msk);
                pd[hd][reg] += __shfl_xor(pd[hd][reg], msk);
            }
    }
    #pragma unroll
    for (int reg = 0; reg < 4; reg++) {
        int row = rowbase + quad * 4 + reg;
        if (row < N) {
            #pragma unroll
            for (int ct = 0; ct < 8; ct++)
                hh[(size_t)row * HD + ct * 16 + n16] = f2b(acc[ct][reg]);
            if (n16 < 4) {
                float ws = 0.f, wd = 0.f;
                #pragma unroll
                for (int hd = 0; hd < 4; hd++)
                    if (n16 == hd) { ws = ps[hd][reg]; wd = pd[hd][reg]; }
                a_src[row * 4 + n16] = ws;
                a_dst[row * 4 + n16] = wd;
            }
        }
    }
}

// ---------------- per-node attention aggregation: batched two-phase gather ----------------
__global__ __launch_bounds__(256) void k_agg(
    u16* __restrict__ h, const u32* __restrict__ hh32,
    const float* __restrict__ a_src, const float* __restrict__ a_dst,
    const int* __restrict__ rowptr, const int* __restrict__ colidx,
    const float* __restrict__ bias, const float* __restrict__ bng, const float* __restrict__ bnb,
    const float* __restrict__ bnm, const float* __restrict__ bnv, int N) {
    __shared__ int   sL[4][64];
    __shared__ __align__(16) float eeL[4][64][4];
    int wv = threadIdx.x >> 6, lane = threadIdx.x & 63;
    int node = blockIdx.x * 4 + wv;
    if (node >= N) return;
    int head = lane >> 4;
    const float4* as4p = (const float4*)a_src;
    float4 ad4 = ((const float4*)a_dst)[node];
    float adh = (head == 0) ? ad4.x : (head == 1) ? ad4.y : (head == 2) ? ad4.z : ad4.w;
    float ash = a_src[node * 4 + head];
    float e = ash + adh;
    e = (e > 0.f) ? e : 0.2f * e;
    float ee = __expf(e);
    float den = ee;
    u32 hv = hh32[(size_t)node * 64 + lane];
    float acc0 = ee * lo16(hv), acc1 = ee * hi16(hv);
    int beg = rowptr[node], end = rowptr[node + 1];
    for (int base = beg; base < end; base += 64) {
        int cnt = end - base; if (cnt > 64) cnt = 64;
        int s = 0;
        float4 e4 = {0.f, 0.f, 0.f, 0.f};
        if (lane < cnt) {
            s = colidx[base + lane];
            float4 as4 = as4p[s];
            float t0 = as4.x + ad4.x, t1 = as4.y + ad4.y, t2 = as4.z + ad4.z, t3 = as4.w + ad4.w;
            t0 = (t0 > 0.f) ? t0 : 0.2f * t0; t1 = (t1 > 0.f) ? t1 : 0.2f * t1;
            t2 = (t2 > 0.f) ? t2 : 0.2f * t2; t3 = (t3 > 0.f) ? t3 : 0.2f * t3;
            e4.x = __expf(t0); e4.y = __expf(t1); e4.z = __expf(t2); e4.w = __expf(t3);
        }
        sL[wv][lane] = s;
        ((float4*)eeL[wv][lane])[0] = e4;
        #pragma unroll 4
        for (int j = 0; j < cnt; j++) {
            int sj = sL[wv][j];
            float w = eeL[wv][j][head];
            u32 hv2 = hh32[(size_t)sj * 64 + lane];
            den += w;
            acc0 += w * lo16(hv2);
            acc1 += w * hi16(hv2);
        }
    }
    float inv = 1.0f / (den + 1e-16f);
    int c0 = lane * 2, c1 = c0 + 1;
    float o0 = acc0 * inv, o1 = acc1 * inv;
    float sc0 = bng[c0] * rsqrtf(bnv[c0] + EPS);
    float sc1 = bng[c1] * rsqrtf(bnv[c1] + EPS);
    o0 = (o0 + bias[c0] - bnm[c0]) * sc0 + bnb[c0];
    o1 = (o1 + bias[c1] - bnm[c1]) * sc1 + bnb[c1];
    o0 = fmaxf(o0, 0.f); o1 = fmaxf(o1, 0.f);
    u32 idv = ((const u32*)h)[(size_t)node * 64 + lane];
    o0 += lo16(idv); o1 += hi16(idv);
    ((u32*)h)[(size_t)node * 64 + lane] = ((u32)f2b(o1) << 16) | f2b(o0);
}

// ---------------- pooling + glob encoder -> z[G,384] f32 ----------------
__global__ __launch_bounds__(256) void k_pool(
    const u16* __restrict__ h, const int* __restrict__ gs,
    const float* __restrict__ gf, const float* __restrict__ glob_w, const float* __restrict__ glob_b,
    const float* __restrict__ gbg, const float* __restrict__ gbb,
    const float* __restrict__ gbm, const float* __restrict__ gbv,
    float* __restrict__ z, int N, int G) {
    __shared__ float s0L[4][64], s1L[4][64], m0L[4][64], m1L[4][64];
    int g = blockIdx.x, tid = threadIdx.x;
    int wv = tid >> 6, lane = tid & 63;
    int beg = gs[g], end = gs[g + 1];
    const u32* h32 = (const u32*)h;
    float s0 = 0.f, s1 = 0.f, m0 = -3.4e38f, m1 = -3.4e38f;
    for (int r = beg + wv; r < end; r += 4) {
        u32 pk = h32[(size_t)r * 64 + lane];
        float v0 = lo16(pk), v1 = hi16(pk);
        s0 += v0; s1 += v1;
        m0 = fmaxf(m0, v0); m1 = fmaxf(m1, v1);
    }
    s0L[wv][lane] = s0; s1L[wv][lane] = s1;
    m0L[wv][lane] = m0; m1L[wv][lane] = m1;
    __syncthreads();
    if (tid < 64) {
        float a0 = s0L[0][lane] + s0L[1][lane] + s0L[2][lane] + s0L[3][lane];
        float a1 = s1L[0][lane] + s1L[1][lane] + s1L[2][lane] + s1L[3][lane];
        float x0 = fmaxf(fmaxf(m0L[0][lane], m0L[1][lane]), fmaxf(m0L[2][lane], m0L[3][lane]));
        float x1 = fmaxf(fmaxf(m1L[0][lane], m1L[1][lane]), fmaxf(m1L[2][lane], m1L[3][lane]));
        int cnt = end - beg;
        float inv = 1.0f / (float)(cnt > 0 ? cnt : 1);
        if (cnt == 0) { x0 = 0.f; x1 = 0.f; }
        ((float2*)(z + (size_t)g * 384))[lane] = make_float2(a0 * inv, a1 * inv);
        ((float2*)(z + (size_t)g * 384 + 128))[lane] = make_float2(x0, x1);
    } else if (tid >= 128) {
        int c = tid - 128;
        float acc = glob_b[c];
        #pragma unroll 8
        for (int k = 0; k < 32; k++) acc += gf[g * 32 + k] * glob_w[k * HD + c];
        float sc = gbg[c] * rsqrtf(gbv[c] + EPS);
        acc = (acc - gbm[c]) * sc + gbb[c];
        z[(size_t)g * 384 + 256 + c] = fmaxf(acc, 0.f);
    }
}

// ---------------- lin1(+relu) . W2 + b2 with LDS-staged W1; 8 graphs/block ----------------
__global__ __launch_bounds__(256) void k_lin(
    const float* __restrict__ z, const float* __restrict__ W1, const float* __restrict__ b1,
    const float* __restrict__ W2, const float* __restrict__ b2, float* __restrict__ out, int G) {
    __shared__ float zL[8][384];    // 12 KB
    __shared__ float Wc[64][128];   // 32 KB
    __shared__ float red[8][128];   // 4 KB
    int tid = threadIdx.x;
    int g0 = blockIdx.x * 8;
    int c = tid & 127, half = tid >> 7;
    for (int i = tid; i < 8 * 384; i += 256) {
        int gi = i / 384, kk = i % 384;
        zL[gi][kk] = (g0 + gi < G) ? z[(size_t)(g0 + gi) * 384 + kk] : 0.f;
    }
    float acc0 = 0.f, acc1 = 0.f, acc2 = 0.f, acc3 = 0.f;
    int gb = half * 4;
    for (int ch = 0; ch < 6; ch++) {
        __syncthreads();
        for (int i4 = tid; i4 < 2048; i4 += 256) {
            int flat = i4 * 4;
            int k = flat >> 7, cc = flat & 127;
            *(float4*)&Wc[k][cc] = *(const float4*)&W1[(size_t)(ch * 64 + k) * HD + cc];
        }
        __syncthreads();
        int kb = ch * 64;
        #pragma unroll 4
        for (int k = 0; k < 64; k++) {
            float w = Wc[k][c];
            acc0 += zL[gb + 0][kb + k] * w;
            acc1 += zL[gb + 1][kb + k] * w;
            acc2 += zL[gb + 2][kb + k] * w;
            acc3 += zL[gb + 3][kb + k] * w;
        }
    }
    float b1c = b1[c], w2c = W2[c];
    __syncthreads();
    red[gb + 0][c] = fmaxf(acc0 + b1c, 0.f) * w2c;
    red[gb + 1][c] = fmaxf(acc1 + b1c, 0.f) * w2c;
    red[gb + 2][c] = fmaxf(acc2 + b1c, 0.f) * w2c;
    red[gb + 3][c] = fmaxf(acc3 + b1c, 0.f) * w2c;
    __syncthreads();
    int gr = tid >> 5, l32 = tid & 31;
    float v = red[gr][l32] + red[gr][l32 + 32] + red[gr][l32 + 64] + red[gr][l32 + 96];
    #pragma unroll
    for (int m = 1; m < 32; m <<= 1) v += __shfl_xor(v, m, 32);
    if (l32 == 0 && g0 + gr < G) out[g0 + gr] = v + b2[0];
}

extern "C" void kernel_launch(void* const* d_in, const int* in_sizes, int n_in,
                              void* d_out, int out_size, void* d_ws, size_t ws_size,
                              hipStream_t stream) {
    (void)n_in; (void)out_size; (void)ws_size;
    const float* x        = (const float*)d_in[0];
    const float* gfeat    = (const float*)d_in[2];
    const int*   ei       = (const int*)d_in[3];
    const int*   batch    = (const int*)d_in[4];
    const float* node_w   = (const float*)d_in[5];
    const float* node_b   = (const float*)d_in[6];
    const float* nbg      = (const float*)d_in[7];
    const float* nbb      = (const float*)d_in[8];
    const float* nbm      = (const float*)d_in[9];
    const float* nbv      = (const float*)d_in[10];
    const float* glob_w   = (const float*)d_in[13];
    const float* glob_b   = (const float*)d_in[14];
    const float* gbg      = (const float*)d_in[15];
    const float* gbb      = (const float*)d_in[16];
    const float* gbm      = (const float*)d_in[17];
    const float* gbv      = (const float*)d_in[18];
    const float* gat_lin  = (const float*)d_in[19];
    const float* gat_asrc = (const float*)d_in[20];
    const float* gat_adst = (const float*)d_in[21];
    const float* gat_bias = (const float*)d_in[22];
    const float* bn_g     = (const float*)d_in[23];
    const float* bn_b     = (const float*)d_in[24];
    const float* bn_m     = (const float*)d_in[25];
    const float* bn_v     = (const float*)d_in[26];
    const float* lin1_w   = (const float*)d_in[27];
    const float* lin1_b   = (const float*)d_in[28];
    const float* lin2_w   = (const float*)d_in[29];
    const float* lin2_b   = (const float*)d_in[30];

    const int N = in_sizes[0] / FD;
    const int E = in_sizes[3] / 2;
    const int G = in_sizes[2] / 32;
    const int* srcp = ei;
    const int* dstp = ei + E;

    int bsh = 8;
    while (((N + (1 << bsh) - 1) >> bsh) > 256) bsh++;
    const int NB = (N + (1 << bsh) - 1) >> bsh;

    char* p = (char*)d_ws;
    auto alloc = [&](size_t bytes) -> char* {
        char* r = p;
        p += (bytes + 255) & ~(size_t)255;
        return r;
    };
    u16*   h       = (u16*)alloc((size_t)N * HD * 2);
    u16*   hh      = (u16*)alloc((size_t)N * HD * 2);
    float* a_src   = (float*)alloc((size_t)N * 4 * 4);
    float* a_dst   = (float*)alloc((size_t)N * 4 * 4);
    int*   rowptr  = (int*)alloc((size_t)(N + 1) * 4);
    char*  zbase   = p;
    int*   cnt     = (int*)alloc((size_t)N * 4);
    int*   fill    = (int*)alloc((size_t)N * 4);
    int*   bcur    = (int*)alloc(256 * 4);
    size_t zbytes  = (size_t)(p - zbase);
    int*   bsum    = (int*)alloc(256 * 4);
    int*   colidx  = (int*)alloc((size_t)E * 4);
    u64*   binned  = (u64*)alloc((size_t)E * 8);
    u16*   wf_node = (u16*)alloc((size_t)FD * HD * 2);
    u16*   wf_gat  = (u16*)alloc((size_t)3 * HD * HD * 2);
    float* z       = (float*)alloc((size_t)G * 384 * 4);
    int*   gs      = (int*)alloc((size_t)(G + 1) * 4);

    hipMemsetAsync(zbase, 0, zbytes, stream);

    k_wprep<<<dim3(32, 4), 256, 0, stream>>>(node_w, gat_lin, wf_node, wf_gat);

    int eb = (E + 255) / 256;
    int SB = (N + 255) / 256;
    k_hist<<<eb, 256, 0, stream>>>(dstp, cnt, E);
    k_scanA<<<SB, 256, 0, stream>>>(cnt, rowptr, bsum, N);
    k_scanB<<<1, 256, 0, stream>>>(bsum, SB);
    k_scanC<<<SB, 256, 0, stream>>>(rowptr, bsum, N);
    k_gbound<<<SB, 256, 0, stream>>>(batch, gs, N, G);

    int numTiles = (E + 4095) / 4096;
    int binAGrid = numTiles < 512 ? numTiles : 512;
    k_binA<<<binAGrid, 256, 0, stream>>>(srcp, dstp, rowptr, bcur, binned, E, bsh, NB, numTiles);
    k_binB<<<NB, 256, 0, stream>>>(binned, rowptr, fill, colidx, N, bsh);

    k_node_mfma<<<(N + 63) / 64, 256, 0, stream>>>(x, wf_node, node_b, nbg, nbb, nbm, nbv, h, N);

    for (int i = 0; i < 3; i++) {
        k_gat_mfma<<<(N + 63) / 64, 256, 0, stream>>>(
            h, wf_gat + (size_t)i * HD * HD,
            gat_asrc + i * HD, gat_adst + i * HD,
            hh, a_src, a_dst, N);
        k_agg<<<(N + 3) / 4, 256, 0, stream>>>(
            h, (const u32*)hh, a_src, a_dst, rowptr, colidx,
            gat_bias + i * HD, bn_g + i * HD, bn_b + i * HD, bn_m + i * HD, bn_v + i * HD, N);
    }

    k_pool<<<G, 256, 0, stream>>>(h, gs, gfeat, glob_w, glob_b, gbg, gbb, gbm, gbv, z, N, G);
    k_lin<<<(G + 7) / 8, 256, 0, stream>>>(z, lin1_w, lin1_b, lin2_w, lin2_b, (float*)d_out, G);
}

// Round 7
// 424.795 us; speedup vs baseline: 1.8280x; 1.0252x over previous
//
#include <hip/hip_runtime.h>
#include <hip/hip_bf16.h>

typedef unsigned short u16;
typedef unsigned int   u32;
typedef unsigned long long u64;

// N=50000, F=64, H=128, HEADS=4, C=32, L=3, E=800000, G=512, DG=32, NC=1
// Float inputs/outputs are FLOAT32; internal node features h/hh are bf16 for MFMA.
#define HD 128
#define FD 64
#define EPS 1e-5f

using bf16x8 = __attribute__((ext_vector_type(8))) short;
using f32x4  = __attribute__((ext_vector_type(4))) float;

__device__ __forceinline__ float b2f(u16 v) { return __uint_as_float(((u32)v) << 16); }
__device__ __forceinline__ u16 f2b(float f) {
    u32 u = __float_as_uint(f);
    return (u16)((u + 0x7FFF + ((u >> 16) & 1)) >> 16);  // RNE
}
__device__ __forceinline__ float lo16(u32 u) { return __uint_as_float(u << 16); }
__device__ __forceinline__ float hi16(u32 u) { return __uint_as_float(u & 0xFFFF0000u); }

__device__ __forceinline__ bf16x8 pack8(const float* p) {
    bf16x8 r;
    #pragma unroll
    for (int j = 0; j < 8; j++) r[j] = (short)f2b(p[j]);
    return r;
}

// ---------------- CSR build: per-node histogram ----------------
__global__ __launch_bounds__(256) void k_hist(const int* __restrict__ dst, int* __restrict__ cnt, int E) {
    int e = blockIdx.x * 256 + threadIdx.x;
    if (e < E) atomicAdd(&cnt[dst[e]], 1);
}

__global__ __launch_bounds__(256) void k_scanA(const int* __restrict__ cnt, int* __restrict__ rowptr,
                                               int* __restrict__ bsum, int N) {
    __shared__ int s[256];
    int tid = threadIdx.x;
    int i = blockIdx.x * 256 + tid;
    s[tid] = (i < N) ? cnt[i] : 0;
    __syncthreads();
    for (int off = 1; off < 256; off <<= 1) {
        int t = (tid >= off) ? s[tid - off] : 0;
        __syncthreads();
        s[tid] += t;
        __syncthreads();
    }
    if (i < N) rowptr[i + 1] = s[tid];
    if (tid == 255) bsum[blockIdx.x] = s[255];
}

__global__ __launch_bounds__(256) void k_scanB(int* __restrict__ bsum, int SB) {
    __shared__ int s[256];
    int tid = threadIdx.x;
    s[tid] = (tid < SB) ? bsum[tid] : 0;
    __syncthreads();
    for (int off = 1; off < 256; off <<= 1) {
        int t = (tid >= off) ? s[tid - off] : 0;
        __syncthreads();
        s[tid] += t;
        __syncthreads();
    }
    if (tid < SB) bsum[tid] = s[tid];
}

__global__ __launch_bounds__(256) void k_scanC(int* __restrict__ rowptr, const int* __restrict__ bsum, int N) {
    int i = blockIdx.x * 256 + threadIdx.x;
    if (i == 0) rowptr[0] = 0;
    if (i < N) {
        int b = i >> 8;
        if (b > 0) rowptr[i + 1] += bsum[b - 1];
    }
}

// ---------------- graph boundaries from sorted batch ----------------
__global__ __launch_bounds__(256) void k_gbound(const int* __restrict__ batch, int* __restrict__ gs, int N, int G) {
    int i = blockIdx.x * 256 + threadIdx.x;
    if (i < N) {
        int b = batch[i];
        if (i == 0) { for (int g = 0; g <= b; g++) gs[g] = 0; }
        else {
            int pb = batch[i - 1];
            for (int g = pb + 1; g <= b; g++) gs[g] = i;
        }
        if (i == N - 1) { for (int g = b + 1; g <= G; g++) gs[g] = N; }
    }
}

// ---------------- binned scatter, pass A: tile counting-sort by bucket ----------------
__global__ __launch_bounds__(256) void k_binA(
    const int* __restrict__ src, const int* __restrict__ dst, const int* __restrict__ rowptr,
    int* __restrict__ bcur, u64* __restrict__ binned, int E, int bsh, int NB, int numTiles) {
    __shared__ u32 os[4096], od[4096];           // 32 KB sorted tile
    __shared__ int hist[256], obase[256], ofs[256], gpos[256];
    int tid = threadIdx.x;
    for (int t = blockIdx.x; t < numTiles; t += gridDim.x) {
        int base = t * 4096;
        int cnt = E - base; if (cnt > 4096) cnt = 4096;
        hist[tid] = 0;
        __syncthreads();
        u32 rs[16], rd[16];
        #pragma unroll
        for (int r = 0; r < 16; r++) {
            int li = r * 256 + tid;
            if (li < cnt) {
                rs[r] = src[base + li];
                rd[r] = dst[base + li];
                atomicAdd(&hist[rd[r] >> bsh], 1);
            }
        }
        __syncthreads();
        // single-wave shfl scan of hist[256] (4 counters per lane)
        if (tid < 64) {
            int h0 = hist[4 * tid], h1 = hist[4 * tid + 1];
            int h2 = hist[4 * tid + 2], h3 = hist[4 * tid + 3];
            int s01 = h0 + h1;
            int loc = s01 + h2 + h3;
            int inc = loc;
            #pragma unroll
            for (int off = 1; off < 64; off <<= 1) {
                int tv = __shfl_up(inc, off);
                if (tid >= off) inc += tv;
            }
            int excl = inc - loc;
            obase[4 * tid] = excl;           ofs[4 * tid] = excl;
            obase[4 * tid + 1] = excl + h0;  ofs[4 * tid + 1] = excl + h0;
            obase[4 * tid + 2] = excl + s01; ofs[4 * tid + 2] = excl + s01;
            obase[4 * tid + 3] = excl + s01 + h2; ofs[4 * tid + 3] = excl + s01 + h2;
        }
        __syncthreads();
        #pragma unroll
        for (int r = 0; r < 16; r++) {
            int li = r * 256 + tid;
            if (li < cnt) {
                int b = rd[r] >> bsh;
                int posn = atomicAdd(&ofs[b], 1);
                os[posn] = rs[r];
                od[posn] = rd[r];
            }
        }
        __syncthreads();
        if (tid < NB && hist[tid] > 0)
            gpos[tid] = rowptr[tid << bsh] + atomicAdd(&bcur[tid], hist[tid]);
        __syncthreads();
        for (int li = tid; li < cnt; li += 256) {
            u32 d = od[li];
            int b = d >> bsh;
            binned[(size_t)gpos[b] + (li - obase[b])] = ((u64)d << 32) | os[li];
        }
        __syncthreads();
    }
}

// ---------------- binned scatter, pass B: one block per bucket, LDS slot counters ----------
__global__ __launch_bounds__(256) void k_binB(
    const u64* __restrict__ binned, const int* __restrict__ rowptr,
    int* __restrict__ colidx, int N, int bsh) {
    __shared__ int lofs[1024];   // supports bsh <= 10
    int b = blockIdx.x;
    int n0 = b << bsh;
    int n1 = (b + 1) << bsh; if (n1 > N) n1 = N;
    int nb = 1 << bsh;
    for (int i = threadIdx.x; i < nb; i += 256) lofs[i] = 0;
    __syncthreads();
    int r0 = rowptr[n0], r1 = rowptr[n1];
    for (int i = r0 + threadIdx.x; i < r1; i += 256) {
        u64 pk = binned[i];
        u32 d = (u32)(pk >> 32), s = (u32)pk;
        int slot = atomicAdd(&lofs[d - n0], 1);
        colidx[rowptr[d] + slot] = (int)s;
    }
}

// ---------------- weight fragment prep (f32 -> bf16 MFMA B-operand) ----------------
__global__ __launch_bounds__(256) void k_wprep(const float* __restrict__ node_w, const float* __restrict__ gat_lin,
                                               u16* __restrict__ wf_node, u16* __restrict__ wf_gat) {
    int y = blockIdx.y;
    const float* src; u16* dst; int K;
    if (y == 0) { src = node_w; dst = wf_node; K = FD; }
    else { src = gat_lin + (size_t)(y - 1) * HD * HD; dst = wf_gat + (size_t)(y - 1) * HD * HD; K = HD; }
    int KT = K >> 5;
    int total = K * HD;
    for (int f = blockIdx.x * 256 + threadIdx.x; f < total; f += gridDim.x * 256) {
        int j = f & 7;
        int lane = (f >> 3) & 63;
        int t = f >> 9;
        int kt = t % KT;
        int ct = t / KT;
        int k = kt * 32 + (lane >> 4) * 8 + j;
        int col = ct * 16 + (lane & 15);
        dst[f] = f2b(src[k * HD + col]);
    }
}

// ---------------- node encoder via MFMA ----------------
__global__ __launch_bounds__(256) void k_node_mfma(
    const float* __restrict__ x, const u16* __restrict__ wf, const float* __restrict__ bias,
    const float* __restrict__ g, const float* __restrict__ bb, const float* __restrict__ m,
    const float* __restrict__ v, u16* __restrict__ h, int N) {
    int wv = threadIdx.x >> 6, lane = threadIdx.x & 63;
    int rowbase = blockIdx.x * 64 + wv * 16;
    if (rowbase >= N) return;
    int n16 = lane & 15, quad = lane >> 4;
    int arow = min(rowbase + n16, N - 1);
    f32x4 acc[8] = {};
    #pragma unroll
    for (int kt = 0; kt < 2; kt++) {
        bf16x8 a = pack8(x + (size_t)arow * FD + kt * 32 + quad * 8);
        #pragma unroll
        for (int ct = 0; ct < 8; ct++) {
            bf16x8 b = *(const bf16x8*)(wf + ((size_t)(ct * 2 + kt) * 64 + lane) * 8);
            acc[ct] = __builtin_amdgcn_mfma_f32_16x16x32_bf16(a, b, acc[ct], 0, 0, 0);
        }
    }
    #pragma unroll
    for (int ct = 0; ct < 8; ct++) {
        int col = ct * 16 + n16;
        float sc = g[col] * rsqrtf(v[col] + EPS);
        float bi = (bias[col] - m[col]) * sc + bb[col];
        #pragma unroll
        for (int reg = 0; reg < 4; reg++) {
            int row = rowbase + quad * 4 + reg;
            if (row < N) h[(size_t)row * HD + col] = f2b(fmaxf(acc[ct][reg] * sc + bi, 0.f));
        }
    }
}

// ---------------- GAT linear via MFMA ----------------
__global__ __launch_bounds__(256) void k_gat_mfma(
    const u16* __restrict__ h, const u16* __restrict__ wf,
    const float* __restrict__ asrcw, const float* __restrict__ adstw,
    u16* __restrict__ hh, float* __restrict__ a_src, float* __restrict__ a_dst, int N) {
    int wv = threadIdx.x >> 6, lane = threadIdx.x & 63;
    int rowbase = blockIdx.x * 64 + wv * 16;
    if (rowbase >= N) return;
    int n16 = lane & 15, quad = lane >> 4;
    int arow = min(rowbase + n16, N - 1);
    f32x4 acc[8] = {};
    #pragma unroll
    for (int kt = 0; kt < 4; kt++) {
        bf16x8 a = *(const bf16x8*)(h + (size_t)arow * HD + kt * 32 + quad * 8);
        #pragma unroll
        for (int ct = 0; ct < 8; ct++) {
            bf16x8 b = *(const bf16x8*)(wf + ((size_t)(ct * 4 + kt) * 64 + lane) * 8);
            acc[ct] = __builtin_amdgcn_mfma_f32_16x16x32_bf16(a, b, acc[ct], 0, 0, 0);
        }
    }
    float asw[8], adw[8];
    #pragma unroll
    for (int ct = 0; ct < 8; ct++) {
        asw[ct] = asrcw[ct * 16 + n16];
        adw[ct] = adstw[ct * 16 + n16];
    }
    float ps[4][4], pd[4][4];
    #pragma unroll
    for (int hd = 0; hd < 4; hd++)
        #pragma unroll
        for (int reg = 0; reg < 4; reg++) {
            ps[hd][reg] = acc[2 * hd][reg] * asw[2 * hd] + acc[2 * hd + 1][reg] * asw[2 * hd + 1];
            pd[hd][reg] = acc[2 * hd][reg] * adw[2 * hd] + acc[2 * hd + 1][reg] * adw[2 * hd + 1];
        }
    #pragma unroll
    for (int msk = 1; msk < 16; msk <<= 1) {
        #pragma unroll
        for (int hd = 0; hd < 4; hd++)
            #pragma unroll
            for (int reg = 0; reg < 4; reg++) {
                ps[hd][reg] += __shfl_xor(ps[hd][reg], msk);
                pd[hd][reg] += __shfl_xor(pd[hd][reg], msk);
            }
    }
    #pragma unroll
    for (int reg = 0; reg < 4; reg++) {
        int row = rowbase + quad * 4 + reg;
        if (row < N) {
            #pragma unroll
            for (int ct = 0; ct < 8; ct++)
                hh[(size_t)row * HD + ct * 16 + n16] = f2b(acc[ct][reg]);
            if (n16 < 4) {
                float ws = 0.f, wd = 0.f;
                #pragma unroll
                for (int hd = 0; hd < 4; hd++)
                    if (n16 == hd) { ws = ps[hd][reg]; wd = pd[hd][reg]; }
                a_src[row * 4 + n16] = ws;
                a_dst[row * 4 + n16] = wd;
            }
        }
    }
}

// ---------------- per-node attention aggregation: 8-wide batched gather ----------------
__global__ __launch_bounds__(256) void k_agg(
    u16* __restrict__ h, const u32* __restrict__ hh32,
    const float* __restrict__ a_src, const float* __restrict__ a_dst,
    const int* __restrict__ rowptr, const int* __restrict__ colidx,
    const float* __restrict__ bias, const float* __restrict__ bng, const float* __restrict__ bnb,
    const float* __restrict__ bnm, const float* __restrict__ bnv, int N) {
    __shared__ int   sL[4][64];
    __shared__ __align__(16) float eeL[4][64][4];
    int wv = threadIdx.x >> 6, lane = threadIdx.x & 63;
    int node = blockIdx.x * 4 + wv;
    if (node >= N) return;
    int head = lane >> 4;
    const float4* as4p = (const float4*)a_src;
    float4 ad4 = ((const float4*)a_dst)[node];
    float adh = (head == 0) ? ad4.x : (head == 1) ? ad4.y : (head == 2) ? ad4.z : ad4.w;
    float ash = a_src[node * 4 + head];
    float e = ash + adh;
    e = (e > 0.f) ? e : 0.2f * e;
    float ee = __expf(e);
    float den = ee;
    u32 hv = hh32[(size_t)node * 64 + lane];
    float acc0 = ee * lo16(hv), acc1 = ee * hi16(hv);
    int beg = rowptr[node], end = rowptr[node + 1];
    for (int base = beg; base < end; base += 64) {
        int cnt = end - base; if (cnt > 64) cnt = 64;
        int s = 0;
        float4 e4 = {0.f, 0.f, 0.f, 0.f};
        if (lane < cnt) {
            s = colidx[base + lane];
            float4 as4 = as4p[s];
            float t0 = as4.x + ad4.x, t1 = as4.y + ad4.y, t2 = as4.z + ad4.z, t3 = as4.w + ad4.w;
            t0 = (t0 > 0.f) ? t0 : 0.2f * t0; t1 = (t1 > 0.f) ? t1 : 0.2f * t1;
            t2 = (t2 > 0.f) ? t2 : 0.2f * t2; t3 = (t3 > 0.f) ? t3 : 0.2f * t3;
            e4.x = __expf(t0); e4.y = __expf(t1); e4.z = __expf(t2); e4.w = __expf(t3);
        }
        sL[wv][lane] = s;
        ((float4*)eeL[wv][lane])[0] = e4;
        // 8-wide batches: 8 independent row-gathers in flight
        int j = 0;
        for (; j + 8 <= cnt; j += 8) {
            u32 hv2[8]; float w[8];
            #pragma unroll
            for (int q = 0; q < 8; q++) {
                int sj = sL[wv][j + q];
                w[q] = eeL[wv][j + q][head];
                hv2[q] = hh32[(size_t)sj * 64 + lane];
            }
            #pragma unroll
            for (int q = 0; q < 8; q++) {
                den += w[q];
                acc0 += w[q] * lo16(hv2[q]);
                acc1 += w[q] * hi16(hv2[q]);
            }
        }
        for (; j < cnt; j++) {
            int sj = sL[wv][j];
            float w = eeL[wv][j][head];
            u32 hv2 = hh32[(size_t)sj * 64 + lane];
            den += w;
            acc0 += w * lo16(hv2);
            acc1 += w * hi16(hv2);
        }
    }
    float inv = 1.0f / (den + 1e-16f);
    int c0 = lane * 2, c1 = c0 + 1;
    float o0 = acc0 * inv, o1 = acc1 * inv;
    float sc0 = bng[c0] * rsqrtf(bnv[c0] + EPS);
    float sc1 = bng[c1] * rsqrtf(bnv[c1] + EPS);
    o0 = (o0 + bias[c0] - bnm[c0]) * sc0 + bnb[c0];
    o1 = (o1 + bias[c1] - bnm[c1]) * sc1 + bnb[c1];
    o0 = fmaxf(o0, 0.f); o1 = fmaxf(o1, 0.f);
    u32 idv = ((const u32*)h)[(size_t)node * 64 + lane];
    o0 += lo16(idv); o1 += hi16(idv);
    ((u32*)h)[(size_t)node * 64 + lane] = ((u32)f2b(o1) << 16) | f2b(o0);
}

// ---------------- pooling + glob encoder -> z[G,384] f32 ----------------
__global__ __launch_bounds__(256) void k_pool(
    const u16* __restrict__ h, const int* __restrict__ gs,
    const float* __restrict__ gf, const float* __restrict__ glob_w, const float* __restrict__ glob_b,
    const float* __restrict__ gbg, const float* __restrict__ gbb,
    const float* __restrict__ gbm, const float* __restrict__ gbv,
    float* __restrict__ z, int N, int G) {
    __shared__ float s0L[4][64], s1L[4][64], m0L[4][64], m1L[4][64];
    int g = blockIdx.x, tid = threadIdx.x;
    int wv = tid >> 6, lane = tid & 63;
    int beg = gs[g], end = gs[g + 1];
    const u32* h32 = (const u32*)h;
    float s0 = 0.f, s1 = 0.f, m0 = -3.4e38f, m1 = -3.4e38f;
    for (int r = beg + wv; r < end; r += 4) {
        u32 pk = h32[(size_t)r * 64 + lane];
        float v0 = lo16(pk), v1 = hi16(pk);
        s0 += v0; s1 += v1;
        m0 = fmaxf(m0, v0); m1 = fmaxf(m1, v1);
    }
    s0L[wv][lane] = s0; s1L[wv][lane] = s1;
    m0L[wv][lane] = m0; m1L[wv][lane] = m1;
    __syncthreads();
    if (tid < 64) {
        float a0 = s0L[0][lane] + s0L[1][lane] + s0L[2][lane] + s0L[3][lane];
        float a1 = s1L[0][lane] + s1L[1][lane] + s1L[2][lane] + s1L[3][lane];
        float x0 = fmaxf(fmaxf(m0L[0][lane], m0L[1][lane]), fmaxf(m0L[2][lane], m0L[3][lane]));
        float x1 = fmaxf(fmaxf(m1L[0][lane], m1L[1][lane]), fmaxf(m1L[2][lane], m1L[3][lane]));
        int cnt = end - beg;
        float inv = 1.0f / (float)(cnt > 0 ? cnt : 1);
        if (cnt == 0) { x0 = 0.f; x1 = 0.f; }
        ((float2*)(z + (size_t)g * 384))[lane] = make_float2(a0 * inv, a1 * inv);
        ((float2*)(z + (size_t)g * 384 + 128))[lane] = make_float2(x0, x1);
    } else if (tid >= 128) {
        int c = tid - 128;
        float acc = glob_b[c];
        #pragma unroll 8
        for (int k = 0; k < 32; k++) acc += gf[g * 32 + k] * glob_w[k * HD + c];
        float sc = gbg[c] * rsqrtf(gbv[c] + EPS);
        acc = (acc - gbm[c]) * sc + gbb[c];
        z[(size_t)g * 384 + 256 + c] = fmaxf(acc, 0.f);
    }
}

// ---------------- lin1(+relu) . W2 + b2 with LDS-staged W1; 8 graphs/block ----------------
__global__ __launch_bounds__(256) void k_lin(
    const float* __restrict__ z, const float* __restrict__ W1, const float* __restrict__ b1,
    const float* __restrict__ W2, const float* __restrict__ b2, float* __restrict__ out, int G) {
    __shared__ float zL[8][384];    // 12 KB
    __shared__ float Wc[64][128];   // 32 KB
    __shared__ float red[8][128];   // 4 KB
    int tid = threadIdx.x;
    int g0 = blockIdx.x * 8;
    int c = tid & 127, half = tid >> 7;
    for (int i = tid; i < 8 * 384; i += 256) {
        int gi = i / 384, kk = i % 384;
        zL[gi][kk] = (g0 + gi < G) ? z[(size_t)(g0 + gi) * 384 + kk] : 0.f;
    }
    float acc0 = 0.f, acc1 = 0.f, acc2 = 0.f, acc3 = 0.f;
    int gb = half * 4;
    for (int ch = 0; ch < 6; ch++) {
        __syncthreads();
        for (int i4 = tid; i4 < 2048; i4 += 256) {
            int flat = i4 * 4;
            int k = flat >> 7, cc = flat & 127;
            *(float4*)&Wc[k][cc] = *(const float4*)&W1[(size_t)(ch * 64 + k) * HD + cc];
        }
        __syncthreads();
        int kb = ch * 64;
        #pragma unroll 4
        for (int k = 0; k < 64; k++) {
            float w = Wc[k][c];
            acc0 += zL[gb + 0][kb + k] * w;
            acc1 += zL[gb + 1][kb + k] * w;
            acc2 += zL[gb + 2][kb + k] * w;
            acc3 += zL[gb + 3][kb + k] * w;
        }
    }
    float b1c = b1[c], w2c = W2[c];
    __syncthreads();
    red[gb + 0][c] = fmaxf(acc0 + b1c, 0.f) * w2c;
    red[gb + 1][c] = fmaxf(acc1 + b1c, 0.f) * w2c;
    red[gb + 2][c] = fmaxf(acc2 + b1c, 0.f) * w2c;
    red[gb + 3][c] = fmaxf(acc3 + b1c, 0.f) * w2c;
    __syncthreads();
    int gr = tid >> 5, l32 = tid & 31;
    float v = red[gr][l32] + red[gr][l32 + 32] + red[gr][l32 + 64] + red[gr][l32 + 96];
    #pragma unroll
    for (int m = 1; m < 32; m <<= 1) v += __shfl_xor(v, m, 32);
    if (l32 == 0 && g0 + gr < G) out[g0 + gr] = v + b2[0];
}

extern "C" void kernel_launch(void* const* d_in, const int* in_sizes, int n_in,
                              void* d_out, int out_size, void* d_ws, size_t ws_size,
                              hipStream_t stream) {
    (void)n_in; (void)out_size; (void)ws_size;
    const float* x        = (const float*)d_in[0];
    const float* gfeat    = (const float*)d_in[2];
    const int*   ei       = (const int*)d_in[3];
    const int*   batch    = (const int*)d_in[4];
    const float* node_w   = (const float*)d_in[5];
    const float* node_b   = (const float*)d_in[6];
    const float* nbg      = (const float*)d_in[7];
    const float* nbb      = (const float*)d_in[8];
    const float* nbm      = (const float*)d_in[9];
    const float* nbv      = (const float*)d_in[10];
    const float* glob_w   = (const float*)d_in[13];
    const float* glob_b   = (const float*)d_in[14];
    const float* gbg      = (const float*)d_in[15];
    const float* gbb      = (const float*)d_in[16];
    const float* gbm      = (const float*)d_in[17];
    const float* gbv      = (const float*)d_in[18];
    const float* gat_lin  = (const float*)d_in[19];
    const float* gat_asrc = (const float*)d_in[20];
    const float* gat_adst = (const float*)d_in[21];
    const float* gat_bias = (const float*)d_in[22];
    const float* bn_g     = (const float*)d_in[23];
    const float* bn_b     = (const float*)d_in[24];
    const float* bn_m     = (const float*)d_in[25];
    const float* bn_v     = (const float*)d_in[26];
    const float* lin1_w   = (const float*)d_in[27];
    const float* lin1_b   = (const float*)d_in[28];
    const float* lin2_w   = (const float*)d_in[29];
    const float* lin2_b   = (const float*)d_in[30];

    const int N = in_sizes[0] / FD;
    const int E = in_sizes[3] / 2;
    const int G = in_sizes[2] / 32;
    const int* srcp = ei;
    const int* dstp = ei + E;

    int bsh = 8;
    while (((N + (1 << bsh) - 1) >> bsh) > 256) bsh++;
    const int NB = (N + (1 << bsh) - 1) >> bsh;

    char* p = (char*)d_ws;
    auto alloc = [&](size_t bytes) -> char* {
        char* r = p;
        p += (bytes + 255) & ~(size_t)255;
        return r;
    };
    u16*   h       = (u16*)alloc((size_t)N * HD * 2);
    u16*   hh      = (u16*)alloc((size_t)N * HD * 2);
    float* a_src   = (float*)alloc((size_t)N * 4 * 4);
    float* a_dst   = (float*)alloc((size_t)N * 4 * 4);
    int*   rowptr  = (int*)alloc((size_t)(N + 1) * 4);
    char*  zbase   = p;
    int*   cnt     = (int*)alloc((size_t)N * 4);
    int*   bcur    = (int*)alloc(256 * 4);
    size_t zbytes  = (size_t)(p - zbase);
    int*   bsum    = (int*)alloc(256 * 4);
    int*   colidx  = (int*)alloc((size_t)E * 4);
    u64*   binned  = (u64*)alloc((size_t)E * 8);
    u16*   wf_node = (u16*)alloc((size_t)FD * HD * 2);
    u16*   wf_gat  = (u16*)alloc((size_t)3 * HD * HD * 2);
    float* z       = (float*)alloc((size_t)G * 384 * 4);
    int*   gs      = (int*)alloc((size_t)(G + 1) * 4);

    hipMemsetAsync(zbase, 0, zbytes, stream);

    k_wprep<<<dim3(32, 4), 256, 0, stream>>>(node_w, gat_lin, wf_node, wf_gat);

    int eb = (E + 255) / 256;
    int SB = (N + 255) / 256;
    k_hist<<<eb, 256, 0, stream>>>(dstp, cnt, E);
    k_scanA<<<SB, 256, 0, stream>>>(cnt, rowptr, bsum, N);
    k_scanB<<<1, 256, 0, stream>>>(bsum, SB);
    k_scanC<<<SB, 256, 0, stream>>>(rowptr, bsum, N);
    k_gbound<<<SB, 256, 0, stream>>>(batch, gs, N, G);

    int numTiles = (E + 4095) / 4096;
    int binAGrid = numTiles < 512 ? numTiles : 512;
    k_binA<<<binAGrid, 256, 0, stream>>>(srcp, dstp, rowptr, bcur, binned, E, bsh, NB, numTiles);
    k_binB<<<NB, 256, 0, stream>>>(binned, rowptr, colidx, N, bsh);

    k_node_mfma<<<(N + 63) / 64, 256, 0, stream>>>(x, wf_node, node_b, nbg, nbb, nbm, nbv, h, N);

    for (int i = 0; i < 3; i++) {
        k_gat_mfma<<<(N + 63) / 64, 256, 0, stream>>>(
            h, wf_gat + (size_t)i * HD * HD,
            gat_asrc + i * HD, gat_adst + i * HD,
            hh, a_src, a_dst, N);
        k_agg<<<(N + 3) / 4, 256, 0, stream>>>(
            h, (const u32*)hh, a_src, a_dst, rowptr, colidx,
            gat_bias + i * HD, bn_g + i * HD, bn_b + i * HD, bn_m + i * HD, bn_v + i * HD, N);
    }

    k_pool<<<G, 256, 0, stream>>>(h, gs, gfeat, glob_w, glob_b, gbg, gbb, gbm, gbv, z, N, G);
    k_lin<<<(G + 7) / 8, 256, 0, stream>>>(z, lin1_w, lin1_b, lin2_w, lin2_b, (float*)d_out, G);
}